// Round 11
// baseline (965.610 us; speedup 1.0000x reference)
//
#include <hip/hip_runtime.h>

typedef unsigned short u16;
typedef __attribute__((ext_vector_type(8))) short bh8;
typedef __attribute__((ext_vector_type(4))) float f4;

__device__ __forceinline__ u16 f2b(float x){
  union { float f; unsigned u; } c; c.f = x;
  unsigned r = (c.u + 0x7FFFu + ((c.u >> 16) & 1u)) >> 16;
  return (u16)r;
}
__device__ __forceinline__ float b2f(u16 h){
  union { unsigned u; float f; } c; c.u = ((unsigned)h) << 16; return c.f;
}
__device__ __forceinline__ void gload16(const void* g, void* l){
  __builtin_amdgcn_global_load_lds((const __attribute__((address_space(1))) void*)g,
                                   (__attribute__((address_space(3))) void*)l, 16, 0, 0);
}

// ---------------- small utility kernels ----------------

__global__ __launch_bounds__(256) void convall_k(const float* __restrict__ hid,
                                                 const float* __restrict__ wq0, const float* __restrict__ wq1,
                                                 const float* __restrict__ wk0, const float* __restrict__ wk1,
                                                 u16* __restrict__ hidB, u16* __restrict__ wqB, u16* __restrict__ wkB){
  long i = (long)blockIdx.x*256 + threadIdx.x;
  const float* src; u16* dst; long off;
  if      (i < 4194304L){ src = hid; dst = hidB;           off = i; }
  else if (i < 5242880L){ src = wq0; dst = wqB;            off = i - 4194304L; }
  else if (i < 6291456L){ src = wq1; dst = wqB + 1048576;  off = i - 5242880L; }
  else if (i < 7340032L){ src = wk0; dst = wkB;            off = i - 6291456L; }
  else                  { src = wk1; dst = wkB + 1048576;  off = i - 7340032L; }
  dst[off] = f2b(src[off]);
}

// uniform prefill ONLY for rows with width==0 (never touched by softmax); both streams
__global__ __launch_bounds__(256) void uniform0_k(const int* __restrict__ spw, float* __restrict__ out){
  int bl = blockIdx.x;              // b*1024 + l, 4096 blocks
  if (spw[bl] != 0) return;
  f4 t = {0.0009765625f, 0.0009765625f, 0.0009765625f, 0.0009765625f};
  float* b0 = out + (size_t)bl*8192;
  float* b1 = out + 33554432ull + (size_t)bl*8192;
  #pragma unroll
  for (int i = 0; i < 8; i++){
    ((f4*)(b0 + (size_t)i*1024))[threadIdx.x] = t;
    ((f4*)(b1 + (size_t)i*1024))[threadIdx.x] = t;
  }
}

// transpose [R][C] f32 -> [C][R] bf16
__global__ __launch_bounds__(256) void trans_k(const float* __restrict__ in, u16* __restrict__ out,
                                               int R, int C){
  __shared__ u16 t[32][33];
  int bx = blockIdx.x*32, by = blockIdx.y*32;
  int tx = threadIdx.x & 31, ty = threadIdx.x >> 5;
  #pragma unroll
  for (int j = 0; j < 32; j += 8) t[ty+j][tx] = f2b(in[(size_t)(by+ty+j)*C + bx+tx]);
  __syncthreads();
  #pragma unroll
  for (int j = 0; j < 32; j += 8) out[(size_t)(bx+ty+j)*R + by+tx] = t[tx][ty+j];
}

// counting sort rows per batch by width descending + emit masks output
__global__ __launch_bounds__(256) void sort_k(const int* __restrict__ spw, int* __restrict__ perm,
                                              int* __restrict__ cnt, float* __restrict__ mout){
  int b = blockIdx.x, t = threadIdx.x;
  __shared__ int hist[9], start[9];
  if (t < 9) hist[t] = 0;
  __syncthreads();
  for (int l = t; l < 1024; l += 256) atomicAdd(&hist[spw[b*1024 + l]], 1);
  __syncthreads();
  if (t == 0){
    int acc = 0;
    for (int w = 8; w >= 0; w--){ start[w] = acc; acc += hist[w]; }
  }
  __syncthreads();
  if (t < 8) cnt[b*8 + t] = start[t];
  __syncthreads();
  for (int l = t; l < 1024; l += 256){
    int w = spw[b*1024 + l];
    float* mo = mout + ((size_t)b*1024 + l)*8;
    #pragma unroll
    for (int i = 0; i < 8; i++) mo[i] = (i < w) ? 1.0f : 0.0f;
    int pos = atomicAdd(&start[w], 1);
    perm[b*1024 + pos] = l;
  }
}

__global__ __launch_bounds__(256) void gather_k(const float* __restrict__ srch, const int* __restrict__ perm,
                                                u16* __restrict__ hb){
  int blk = blockIdx.x;             // z*1024 + c
  int z = blk >> 10, c = blk & 1023, b = z & 3;
  int ro = perm[b*1024 + c];
  const float* src = srch + ((size_t)b*1024 + ro)*1024;
  u16* dst = hb + ((size_t)z*1024 + c)*1024;
  for (int d = threadIdx.x; d < 1024; d += 256) dst[d] = f2b(src[d]);
}

// Mx rel rows: Mx[z][1024+r][e] = (1/32)*sum_k wq_s[e][k]*rel_s[r][k], written to all 4 b of s
__global__ __launch_bounds__(256) void wrt_k(const float* __restrict__ wq0, const float* __restrict__ wq1,
                                             const float* __restrict__ rel0, const float* __restrict__ rel1,
                                             u16* __restrict__ Mx){
  long idx = (long)blockIdx.x*256 + threadIdx.x;
  if (idx >= 2L*33*1024) return;
  int s = idx >= 33*1024; long loc = idx - (s ? 33*1024 : 0);
  int r = (int)(loc >> 10), e = (int)(loc & 1023);
  const float* wqrow = (s ? wq1 : wq0) + (size_t)e*1024;
  const float* rel = (s ? rel1 : rel0) + (size_t)r*1024;
  float acc = 0.0f;
  #pragma unroll 4
  for (int k = 0; k < 1024; k++) acc += wqrow[k]*rel[k];
  u16 v = f2b(acc*0.03125f);
  size_t o = (size_t)(1024 + r)*1024 + e;
  #pragma unroll
  for (int b = 0; b < 4; b++)
    Mx[(size_t)(s*4 + b)*1179648 + o] = v;
}

// merged dot products (see round-4 comment)
__global__ __launch_bounds__(256) void dots_k(const float* __restrict__ wq0, const float* __restrict__ wq1,
                                              const float* __restrict__ wk0, const float* __restrict__ wk1,
                                              const float* __restrict__ bq0, const float* __restrict__ bq1,
                                              const float* __restrict__ bk0, const float* __restrict__ bk1,
                                              const float* __restrict__ rel0, const float* __restrict__ rel1,
                                              float* __restrict__ ubuf, float* __restrict__ c0buf,
                                              float* __restrict__ bqbk, float* __restrict__ cba){
  int row = blockIdx.x*4 + (threadIdx.x >> 6);
  int lane = threadIdx.x & 63;
  if (row >= 4164) return;
  const float *a, *v;
  int kind = 0, oi = 0, br_s = 0, br_r = 0;
  if      (row < 1024){ a = wk0 + (size_t)row*1024; v = bq0; oi = row; }
  else if (row < 2048){ a = wk1 + (size_t)(row-1024)*1024; v = bq1; oi = row; }
  else if (row < 3072){ a = wq0 + (size_t)(row-2048)*1024; v = bk0; kind = 1; oi = row-2048; }
  else if (row < 4096){ a = wq1 + (size_t)(row-3072)*1024; v = bk1; kind = 1; oi = row-3072+1024; }
  else if (row < 4162){ int idx = row-4096; br_s = idx/33; br_r = idx%33;
                        a = (br_s ? rel1 : rel0) + (size_t)br_r*1024; v = br_s ? bq1 : bq0; kind = 2; }
  else                { int s2 = row-4162; a = s2 ? bq1 : bq0; v = s2 ? bk1 : bk0; kind = 3; oi = s2; }
  const f4* ap = (const f4*)a;
  const f4* vp = (const f4*)v;
  float acc = 0.0f;
  #pragma unroll
  for (int p = 0; p < 4; p++){
    f4 x = ap[lane + 64*p], y = vp[lane + 64*p];
    acc += x[0]*y[0] + x[1]*y[1] + x[2]*y[2] + x[3]*y[3];
  }
  #pragma unroll
  for (int off = 32; off > 0; off >>= 1) acc += __shfl_xor(acc, off, 64);
  if (lane == 0){
    if (kind == 0) ubuf[oi] = acc;
    else if (kind == 1) c0buf[oi] = acc;
    else if (kind == 2){
      float w = acc*0.03125f;
      for (int b = 0; b < 4; b++) cba[(br_s*4 + b)*1152 + 1024 + br_r] = w;
    } else bqbk[oi] = acc;
  }
}

// cba[z*1152+l] = (hid[b][l].u_s + bqbk_s)/32
__global__ __launch_bounds__(256) void cba_k(const float* __restrict__ hid, const float* __restrict__ u,
                                             const float* __restrict__ bqbk, float* __restrict__ cba){
  int row = blockIdx.x*4 + (threadIdx.x >> 6);  // z*1024+l
  int lane = threadIdx.x & 63;
  int z = row >> 10, l = row & 1023, b = z & 3, s = z >> 2;
  const f4* hp = (const f4*)(hid + ((size_t)b*1024 + l)*1024);
  const f4* up = (const f4*)(u + s*1024);
  float acc = 0.0f;
  #pragma unroll
  for (int p = 0; p < 4; p++){
    f4 a = hp[lane + 64*p], c = up[lane + 64*p];
    acc += a[0]*c[0] + a[1]*c[1] + a[2]*c[2] + a[3]*c[3];
  }
  #pragma unroll
  for (int off = 32; off > 0; off >>= 1) acc += __shfl_xor(acc, off, 64);
  if (!lane) cba[z*1152 + l] = (acc + bqbk[s])*0.03125f;
}

// meanH2[b*1024+d] = (1/1024) * sum_l H2T[b][d][l]
__global__ __launch_bounds__(256) void meanh2_k(const u16* __restrict__ H2T, float* __restrict__ mh){
  int row = blockIdx.x*4 + (threadIdx.x >> 6);
  int lane = threadIdx.x & 63;
  const u16* p = H2T + (size_t)row*1024 + lane*16;
  float s = 0.0f;
  #pragma unroll
  for (int j = 0; j < 16; j++) s += b2f(p[j]);
  #pragma unroll
  for (int off = 32; off > 0; off >>= 1) s += __shfl_xor(s, off, 64);
  if (lane == 0) mh[row] = s * 0.0009765625f;
}

// row softmax: bf16 scores + rel gather -> probs f32 (d_out) + bf16 attnP;
// a row's LAST active iter (iter == w-1) also writes its uniform tail slots w..7
__global__ __launch_bounds__(256) void softmax_k(const u16* __restrict__ scB, float* __restrict__ outF,
                                                 u16* __restrict__ attnP, const float* __restrict__ qrelb,
                                                 const int* __restrict__ cnt, const int* __restrict__ perm,
                                                 const int* __restrict__ spw, int iter){
  int z = blockIdx.x >> 10, c = blockIdx.x & 1023;
  int s = z >> 2, b = z & 3;
  if (c >= cnt[b*8 + iter]) return;
  int ro = perm[b*1024 + c];
  __shared__ float qr[33];
  __shared__ float red[8];
  if (threadIdx.x < 33) qr[threadIdx.x] = qrelb[((size_t)z*1024 + c)*33 + threadIdx.x];
  __syncthreads();
  const u16* sc = scB + ((size_t)z*1024 + c)*1024;
  float* po = outF + (size_t)s*33554432ull + (((size_t)(b*1024 + ro))*8 + (size_t)iter)*1024;
  u16* pr = attnP + ((size_t)z*1024 + c)*1024;
  int t = threadIdx.x;
  float v[4]; float mx = -1e30f;
  #pragma unroll
  for (int j = 0; j < 4; j++){
    int col = t + j*256;
    int d = col - ro; d = d < -16 ? -16 : (d > 16 ? 16 : d);
    v[j] = b2f(sc[col]) + qr[d + 16];
    mx = fmaxf(mx, v[j]);
  }
  #pragma unroll
  for (int off = 32; off > 0; off >>= 1) mx = fmaxf(mx, __shfl_xor(mx, off, 64));
  int wv = t >> 6, ln = t & 63;
  if (ln == 0) red[wv] = mx;
  __syncthreads();
  mx = fmaxf(fmaxf(red[0], red[1]), fmaxf(red[2], red[3]));
  float sm = 0.0f;
  #pragma unroll
  for (int j = 0; j < 4; j++){ v[j] = __expf(v[j] - mx); sm += v[j]; }
  #pragma unroll
  for (int off = 32; off > 0; off >>= 1) sm += __shfl_xor(sm, off, 64);
  if (ln == 0) red[4 + wv] = sm;
  __syncthreads();
  sm = red[4] + red[5] + red[6] + red[7];
  float inv = 1.0f / sm;
  #pragma unroll
  for (int j = 0; j < 4; j++){
    float pv = v[j] * inv;
    po[t + j*256] = pv;
    pr[t + j*256] = f2b(pv);
  }
  int w = spw[b*1024 + ro];
  if (iter == w - 1 && w < 8){
    f4 u = {0.0009765625f, 0.0009765625f, 0.0009765625f, 0.0009765625f};
    for (int j = 1; j <= 7 - iter; j++)
      ((f4*)(po + (size_t)j*1024))[t] = u;
  }
}

// ---------------- MFMA GEMM, 128x128 tile, BK=64, depth-2 counted-vmcnt + swizzle + setprio
// + split-half ds/MFMA overlap: read h0 -> read h1 -> lgkm(8) -> MFMA(h0) [h1 completes under]
// -> lgkm(0) -> release barrier -> stage(t+2) -> MFMA(h1). All reads precede the release
// barrier (sync semantics preserved); sched_barrier(0) pins group order (rule #18).
template<int MODE>
__global__ __launch_bounds__(256) void gemm_k(
    const u16* __restrict__ A_, const u16* __restrict__ B_,
    const u16* __restrict__ A2_, const u16* __restrict__ B2_,
    const float* __restrict__ e0, const float* __restrict__ e1,
    u16* __restrict__ outB, float* __restrict__ qrelb,
    const int* __restrict__ cnt, int iter)
{
  const int z = blockIdx.z;
  const int s = (MODE == 1) ? 0 : (z >> 2);
  const int b = (MODE == 1) ? z : (z & 3);
  const size_t LD = 1024*1024;
  const int bm = blockIdx.y*128, bn = blockIdx.x*128;

  int cntv = 1024;
  if constexpr (MODE == 2 || MODE == 4){
    cntv = cnt[b*8 + iter];
    if (bm >= cntv) return;
  }

  const u16 *A1, *B1, *A2, *B2;
  int lda1 = 1024, ldb1 = 1024, lda2 = 1024, ldb2 = 1024, K = 1024, K1 = 1024;

  if constexpr (MODE == 0){ A1 = A_ + (size_t)z*LD; B1 = B_ + (size_t)z*LD; A2=A1; B2=B1; }
  else if constexpr (MODE == 1){ A1 = A_ + 1024; lda1 = 2048; B1 = B_ + (size_t)z*LD; A2=A1; B2=B1; lda2=lda1; }
  else if constexpr (MODE == 2){
    A1 = A_ + (size_t)z*LD; B1 = B_ + (size_t)b*LD;
    A2 = A2_ + (size_t)z*LD; B2 = B2_; ldb2 = 2048;
    if (iter == 0){ K = 1024; K1 = 0; } else { K = 2048; K1 = 1024; }
  }
  else if constexpr (MODE == 3){ A1 = A_ + (size_t)b*LD; B1 = B_ + (size_t)s*LD; A2=A1; B2=B1; }
  else { A1 = A_ + (size_t)z*LD; B1 = B_ + (size_t)z*1179648; A2=A1; B2=B1; }

  // 2 bufs x [2 K-halves][128 rows][32 cols] bf16 = 2 x 16 KB per operand (64 KB total)
  __shared__ __align__(16) u16 lA[16384];
  __shared__ __align__(16) u16 lB[16384];
  const int tid = threadIdx.x, wv = tid >> 6, lane = tid & 63;
  const int wr = (wv >> 1)*64, wc = (wv & 1)*64;
  const int fr = lane & 15, kh = lane >> 4;
  const int stRow = (lane >> 2);
  // T2 swizzle both-sides (rule #21): 16B slot' = slot ^ ((row&3)^((row>>2)&3))
  const int ssw  = ((lane >> 2) & 3) ^ ((lane >> 4) & 3);
  const int stCe = ((lane & 3) ^ ssw)*8;
  const int fsw  = (fr & 3) ^ ((fr >> 2) & 3);
  const int rdSl = (kh ^ fsw)*8;

  auto stage = [&](int bufsel, int k0s){
    const u16 *As, *Bs; int kk, la, lb;
    if (k0s < K1){ As = A1; Bs = B1; kk = k0s; la = lda1; lb = ldb1; }
    else         { As = A2; Bs = B2; kk = k0s - K1; la = lda2; lb = ldb2; }
    #pragma unroll
    for (int c = 0; c < 4; c++){
      const int n = wv*4 + c;                 // chunk 0..15 (1KB each)
      const int h = n >> 3;
      const int rl = (n & 7)*16 + stRow;
      const int ke = kk + h*32 + stCe;
      gload16(As + (size_t)(bm + rl)*la + ke, (char*)lA + bufsel*16384 + n*1024);
      gload16(Bs + (size_t)(bn + rl)*lb + ke, (char*)lB + bufsel*16384 + n*1024);
    }
  };

  f4 acc[4][4];
  #pragma unroll
  for (int i = 0; i < 4; i++)
    #pragma unroll
    for (int j = 0; j < 4; j++)
      acc[i][j] = f4{0.f, 0.f, 0.f, 0.f};

  stage(0, 0);
  stage(1, 64);               // K >= 128 always here

  int cur = 0;
  for (int k0 = 0; k0 < K; k0 += 64){
    // stage(t) landed (8 own loads of stage(t+1) may remain in flight)
    if (k0 + 64 < K) asm volatile("s_waitcnt vmcnt(8)" ::: "memory");
    else             asm volatile("s_waitcnt vmcnt(0)" ::: "memory");
    __builtin_amdgcn_s_barrier();           // all waves' stage(t) visible
    asm volatile("" ::: "memory");
    const u16* bufA = lA + cur*8192;
    const u16* bufB = lB + cur*8192;
    bh8 af[2][4], bfr[2][4];
    #pragma unroll
    for (int i = 0; i < 4; i++){
      af[0][i]  = *(const bh8*)&bufA[(wr + i*16 + fr)*32 + rdSl];
      bfr[0][i] = *(const bh8*)&bufB[(wc + i*16 + fr)*32 + rdSl];
    }
    __builtin_amdgcn_sched_barrier(0);      // pin h0 reads before h1 reads
    #pragma unroll
    for (int i = 0; i < 4; i++){
      af[1][i]  = *(const bh8*)&bufA[4096 + (wr + i*16 + fr)*32 + rdSl];
      bfr[1][i] = *(const bh8*)&bufB[4096 + (wc + i*16 + fr)*32 + rdSl];
    }
    asm volatile("s_waitcnt lgkmcnt(8)" ::: "memory");   // h0 frags ready
    __builtin_amdgcn_sched_barrier(0);
    __builtin_amdgcn_s_setprio(1);
    #pragma unroll
    for (int i = 0; i < 4; i++)
      #pragma unroll
      for (int j = 0; j < 4; j++)
        acc[i][j] = __builtin_amdgcn_mfma_f32_16x16x32_bf16(af[0][i], bfr[0][j], acc[i][j], 0, 0, 0);
    __builtin_amdgcn_s_setprio(0);
    asm volatile("s_waitcnt lgkmcnt(0)" ::: "memory");   // all my reads done
    __builtin_amdgcn_sched_barrier(0);
    __builtin_amdgcn_s_barrier();           // all waves done reading buf[cur]
    asm volatile("" ::: "memory");
    if (k0 + 128 < K) stage(cur, k0 + 128); // refill buf[cur] for step t+2
    __builtin_amdgcn_s_setprio(1);
    #pragma unroll
    for (int i = 0; i < 4; i++)
      #pragma unroll
      for (int j = 0; j < 4; j++)
        acc[i][j] = __builtin_amdgcn_mfma_f32_16x16x32_bf16(af[1][i], bfr[1][j], acc[i][j], 0, 0, 0);
    __builtin_amdgcn_s_setprio(0);
    cur ^= 1;
  }

  const int rw = (lane >> 4)*4, cl = lane & 15;
  #pragma unroll
  for (int i = 0; i < 4; i++){
    #pragma unroll
    for (int r = 0; r < 4; r++){
      const int row = bm + wr + i*16 + rw + r;
      if constexpr (MODE == 2 || MODE == 4){ if (row >= cntv) continue; }
      #pragma unroll
      for (int j = 0; j < 4; j++){
        const int col = bn + wc + j*16 + cl;
        float v = acc[i][j][r];
        if constexpr (MODE == 0 || MODE == 1){
          outB[(size_t)z*LD + (size_t)row*1024 + col] = f2b(v);
        } else if constexpr (MODE == 2){
          v += e0[col];
          if (e1) v += e1[b*1024 + col];
          v = fmaxf(v, 0.0f);
          outB[(size_t)z*LD + (size_t)row*1024 + col] = f2b(v);
        } else if constexpr (MODE == 3){
          outB[(size_t)z*1179648 + (size_t)row*1024 + col] = f2b((v + e0[s*1024 + col])*0.03125f);
        } else {
          v += e0[z*1152 + col];
          if (col < 1024){
            outB[((size_t)z*1024 + row)*1024 + col] = f2b(v);
          } else {
            int rr = col - 1024;
            if (rr < 33) qrelb[((size_t)z*1024 + row)*33 + rr] = v;
          }
        }
      }
    }
  }
}

// ---------------- host ----------------

extern "C" void kernel_launch(void* const* d_in, const int* in_sizes, int n_in,
                              void* d_out, int out_size, void* d_ws, size_t ws_size,
                              hipStream_t stream)
{
  const float* hid    = (const float*)d_in[0];
  const float* srch   = (const float*)d_in[1];
  const int*   spw    = (const int*)d_in[2];
  const float* wq_st  = (const float*)d_in[6];
  const float* bq_st  = (const float*)d_in[7];
  const float* wk_st  = (const float*)d_in[8];
  const float* bk_st  = (const float*)d_in[9];
  const float* rel_st = (const float*)d_in[10];
  const float* wq_ed  = (const float*)d_in[11];
  const float* bq_ed  = (const float*)d_in[12];
  const float* wk_ed  = (const float*)d_in[13];
  const float* bk_ed  = (const float*)d_in[14];
  const float* rel_ed = (const float*)d_in[15];
  const float* sp_w   = (const float*)d_in[16];
  const float* sp_b   = (const float*)d_in[17];
  float* out = (float*)d_out;

  const size_t LD = 1024*1024;
  char* p = (char*)d_ws;
  u16* hidB  = (u16*)p; p += 4*LD*2;
  u16* wqB   = (u16*)p; p += 2*LD*2;
  u16* wkB   = (u16*)p; p += 2*LD*2;
  u16* spwT  = (u16*)p; p += 2*LD*2;
  u16* WT    = (u16*)p; p += 2*LD*2;
  u16* H2T   = (u16*)p; p += 4*LD*2;
  u16* Mx    = (u16*)p; p += 8ull*1179648*2;      // 8 x [1152][1024]
  u16* attnP = (u16*)p; p += 8*LD*2;
  u16* hbufA = (u16*)p; p += 8*LD*2;
  u16* hbufB = (u16*)p; p += 8*LD*2;
  u16* scB   = (u16*)p; p += 8*LD*2;
  float* qrelb  = (float*)p; p += 8*1024*33*4;
  float* cba    = (float*)p; p += 8*1152*4;
  float* ubuf   = (float*)p; p += 2048*4;
  float* c0buf  = (float*)p; p += 2048*4;
  float* bqbk   = (float*)p; p += 64;
  float* meanH2 = (float*)p; p += 4*1024*4;
  int*   perm   = (int*)p;   p += 4*1024*4;
  int*   cnt    = (int*)p;   p += 1024;

  const dim3 t256(256);

  // --- precompute ---
  convall_k<<<32768, t256, 0, stream>>>(hid, wq_st, wq_ed, wk_st, wk_ed, hidB, wqB, wkB);
  sort_k<<<4, t256, 0, stream>>>(spw, perm, cnt, out + 67108864ull);
  gather_k<<<8192, t256, 0, stream>>>(srch, perm, hbufA);
  uniform0_k<<<4096, t256, 0, stream>>>(spw, out);
  trans_k<<<dim3(32,64), t256, 0, stream>>>(sp_w, spwT, 2048, 1024);
  wrt_k<<<264, t256, 0, stream>>>(wq_st, wq_ed, rel_st, rel_ed, Mx);
  dots_k<<<1041, t256, 0, stream>>>(wq_st, wq_ed, wk_st, wk_ed, bq_st, bq_ed, bk_st, bk_ed,
                                    rel_st, rel_ed, ubuf, c0buf, bqbk, cba);
  cba_k<<<2048, t256, 0, stream>>>(hid, ubuf, bqbk, cba);

  gemm_k<0><<<dim3(8,8,2), t256, 0, stream>>>(wqB, wkB, nullptr, nullptr, nullptr, nullptr,
                                              WT, nullptr, nullptr, 0);
  gemm_k<3><<<dim3(8,8,8), t256, 0, stream>>>(hidB, WT, nullptr, nullptr, c0buf, nullptr,
                                              Mx, nullptr, nullptr, 0);
  gemm_k<1><<<dim3(8,8,4), t256, 0, stream>>>(spwT, hidB, nullptr, nullptr, nullptr, nullptr,
                                              H2T, nullptr, nullptr, 0);
  meanh2_k<<<1024, t256, 0, stream>>>(H2T, meanH2);

  u16* hp = hbufA; u16* hn = hbufB;
  for (int i = 0; i < 8; i++){
    gemm_k<2><<<dim3(8,8,8), t256, 0, stream>>>(attnP, H2T, hp, spwT, sp_b,
                                                (i == 0) ? meanH2 : nullptr,
                                                hn, nullptr, cnt, i);
    gemm_k<4><<<dim3(9,8,8), t256, 0, stream>>>(hn, Mx, nullptr, nullptr, cba, nullptr,
                                                scB, qrelb, cnt, i);
    softmax_k<<<8192, t256, 0, stream>>>(scB, out, attnP, qrelb, cnt, perm, spw, i);
    u16* tmp = hp; hp = hn; hn = tmp;
  }
}

// Round 12
// 919.103 us; speedup vs baseline: 1.0506x; 1.0506x over previous
//
#include <hip/hip_runtime.h>

typedef unsigned short u16;
typedef __attribute__((ext_vector_type(8))) short bh8;
typedef __attribute__((ext_vector_type(4))) float f4;

__device__ __forceinline__ u16 f2b(float x){
  union { float f; unsigned u; } c; c.f = x;
  unsigned r = (c.u + 0x7FFFu + ((c.u >> 16) & 1u)) >> 16;
  return (u16)r;
}
__device__ __forceinline__ float b2f(u16 h){
  union { unsigned u; float f; } c; c.u = ((unsigned)h) << 16; return c.f;
}
__device__ __forceinline__ void gload16(const void* g, void* l){
  __builtin_amdgcn_global_load_lds((const __attribute__((address_space(1))) void*)g,
                                   (__attribute__((address_space(3))) void*)l, 16, 0, 0);
}

// ---------------- small utility kernels ----------------

__global__ __launch_bounds__(256) void convall_k(const float* __restrict__ hid,
                                                 const float* __restrict__ wq0, const float* __restrict__ wq1,
                                                 const float* __restrict__ wk0, const float* __restrict__ wk1,
                                                 u16* __restrict__ hidB, u16* __restrict__ wqB, u16* __restrict__ wkB){
  long i = (long)blockIdx.x*256 + threadIdx.x;
  const float* src; u16* dst; long off;
  if      (i < 4194304L){ src = hid; dst = hidB;           off = i; }
  else if (i < 5242880L){ src = wq0; dst = wqB;            off = i - 4194304L; }
  else if (i < 6291456L){ src = wq1; dst = wqB + 1048576;  off = i - 5242880L; }
  else if (i < 7340032L){ src = wk0; dst = wkB;            off = i - 6291456L; }
  else                  { src = wk1; dst = wkB + 1048576;  off = i - 7340032L; }
  dst[off] = f2b(src[off]);
}

// uniform prefill ONLY for rows with width==0 (never touched by softmax); both streams
__global__ __launch_bounds__(256) void uniform0_k(const int* __restrict__ spw, float* __restrict__ out){
  int bl = blockIdx.x;              // b*1024 + l, 4096 blocks
  if (spw[bl] != 0) return;
  f4 t = {0.0009765625f, 0.0009765625f, 0.0009765625f, 0.0009765625f};
  float* b0 = out + (size_t)bl*8192;
  float* b1 = out + 33554432ull + (size_t)bl*8192;
  #pragma unroll
  for (int i = 0; i < 8; i++){
    ((f4*)(b0 + (size_t)i*1024))[threadIdx.x] = t;
    ((f4*)(b1 + (size_t)i*1024))[threadIdx.x] = t;
  }
}

// transpose [R][C] f32 -> [C][R] bf16
__global__ __launch_bounds__(256) void trans_k(const float* __restrict__ in, u16* __restrict__ out,
                                               int R, int C){
  __shared__ u16 t[32][33];
  int bx = blockIdx.x*32, by = blockIdx.y*32;
  int tx = threadIdx.x & 31, ty = threadIdx.x >> 5;
  #pragma unroll
  for (int j = 0; j < 32; j += 8) t[ty+j][tx] = f2b(in[(size_t)(by+ty+j)*C + bx+tx]);
  __syncthreads();
  #pragma unroll
  for (int j = 0; j < 32; j += 8) out[(size_t)(bx+ty+j)*R + by+tx] = t[tx][ty+j];
}

// counting sort rows per batch by width descending + emit masks output
__global__ __launch_bounds__(256) void sort_k(const int* __restrict__ spw, int* __restrict__ perm,
                                              int* __restrict__ cnt, float* __restrict__ mout){
  int b = blockIdx.x, t = threadIdx.x;
  __shared__ int hist[9], start[9];
  if (t < 9) hist[t] = 0;
  __syncthreads();
  for (int l = t; l < 1024; l += 256) atomicAdd(&hist[spw[b*1024 + l]], 1);
  __syncthreads();
  if (t == 0){
    int acc = 0;
    for (int w = 8; w >= 0; w--){ start[w] = acc; acc += hist[w]; }
  }
  __syncthreads();
  if (t < 8) cnt[b*8 + t] = start[t];
  __syncthreads();
  for (int l = t; l < 1024; l += 256){
    int w = spw[b*1024 + l];
    float* mo = mout + ((size_t)b*1024 + l)*8;
    #pragma unroll
    for (int i = 0; i < 8; i++) mo[i] = (i < w) ? 1.0f : 0.0f;
    int pos = atomicAdd(&start[w], 1);
    perm[b*1024 + pos] = l;
  }
}

__global__ __launch_bounds__(256) void gather_k(const float* __restrict__ srch, const int* __restrict__ perm,
                                                u16* __restrict__ hb){
  int blk = blockIdx.x;             // z*1024 + c
  int z = blk >> 10, c = blk & 1023, b = z & 3;
  int ro = perm[b*1024 + c];
  const float* src = srch + ((size_t)b*1024 + ro)*1024;
  u16* dst = hb + ((size_t)z*1024 + c)*1024;
  for (int d = threadIdx.x; d < 1024; d += 256) dst[d] = f2b(src[d]);
}

// Mx rel rows: Mx[z][1024+r][e] = (1/32)*sum_k wq_s[e][k]*rel_s[r][k], written to all 4 b of s
__global__ __launch_bounds__(256) void wrt_k(const float* __restrict__ wq0, const float* __restrict__ wq1,
                                             const float* __restrict__ rel0, const float* __restrict__ rel1,
                                             u16* __restrict__ Mx){
  long idx = (long)blockIdx.x*256 + threadIdx.x;
  if (idx >= 2L*33*1024) return;
  int s = idx >= 33*1024; long loc = idx - (s ? 33*1024 : 0);
  int r = (int)(loc >> 10), e = (int)(loc & 1023);
  const float* wqrow = (s ? wq1 : wq0) + (size_t)e*1024;
  const float* rel = (s ? rel1 : rel0) + (size_t)r*1024;
  float acc = 0.0f;
  #pragma unroll 4
  for (int k = 0; k < 1024; k++) acc += wqrow[k]*rel[k];
  u16 v = f2b(acc*0.03125f);
  size_t o = (size_t)(1024 + r)*1024 + e;
  #pragma unroll
  for (int b = 0; b < 4; b++)
    Mx[(size_t)(s*4 + b)*1179648 + o] = v;
}

// merged dot products (see round-4 comment)
__global__ __launch_bounds__(256) void dots_k(const float* __restrict__ wq0, const float* __restrict__ wq1,
                                              const float* __restrict__ wk0, const float* __restrict__ wk1,
                                              const float* __restrict__ bq0, const float* __restrict__ bq1,
                                              const float* __restrict__ bk0, const float* __restrict__ bk1,
                                              const float* __restrict__ rel0, const float* __restrict__ rel1,
                                              float* __restrict__ ubuf, float* __restrict__ c0buf,
                                              float* __restrict__ bqbk, float* __restrict__ cba){
  int row = blockIdx.x*4 + (threadIdx.x >> 6);
  int lane = threadIdx.x & 63;
  if (row >= 4164) return;
  const float *a, *v;
  int kind = 0, oi = 0, br_s = 0, br_r = 0;
  if      (row < 1024){ a = wk0 + (size_t)row*1024; v = bq0; oi = row; }
  else if (row < 2048){ a = wk1 + (size_t)(row-1024)*1024; v = bq1; oi = row; }
  else if (row < 3072){ a = wq0 + (size_t)(row-2048)*1024; v = bk0; kind = 1; oi = row-2048; }
  else if (row < 4096){ a = wq1 + (size_t)(row-3072)*1024; v = bk1; kind = 1; oi = row-3072+1024; }
  else if (row < 4162){ int idx = row-4096; br_s = idx/33; br_r = idx%33;
                        a = (br_s ? rel1 : rel0) + (size_t)br_r*1024; v = br_s ? bq1 : bq0; kind = 2; }
  else                { int s2 = row-4162; a = s2 ? bq1 : bq0; v = s2 ? bk1 : bk0; kind = 3; oi = s2; }
  const f4* ap = (const f4*)a;
  const f4* vp = (const f4*)v;
  float acc = 0.0f;
  #pragma unroll
  for (int p = 0; p < 4; p++){
    f4 x = ap[lane + 64*p], y = vp[lane + 64*p];
    acc += x[0]*y[0] + x[1]*y[1] + x[2]*y[2] + x[3]*y[3];
  }
  #pragma unroll
  for (int off = 32; off > 0; off >>= 1) acc += __shfl_xor(acc, off, 64);
  if (lane == 0){
    if (kind == 0) ubuf[oi] = acc;
    else if (kind == 1) c0buf[oi] = acc;
    else if (kind == 2){
      float w = acc*0.03125f;
      for (int b = 0; b < 4; b++) cba[(br_s*4 + b)*1152 + 1024 + br_r] = w;
    } else bqbk[oi] = acc;
  }
}

// cba[z*1152+l] = (hid[b][l].u_s + bqbk_s)/32
__global__ __launch_bounds__(256) void cba_k(const float* __restrict__ hid, const float* __restrict__ u,
                                             const float* __restrict__ bqbk, float* __restrict__ cba){
  int row = blockIdx.x*4 + (threadIdx.x >> 6);  // z*1024+l
  int lane = threadIdx.x & 63;
  int z = row >> 10, l = row & 1023, b = z & 3, s = z >> 2;
  const f4* hp = (const f4*)(hid + ((size_t)b*1024 + l)*1024);
  const f4* up = (const f4*)(u + s*1024);
  float acc = 0.0f;
  #pragma unroll
  for (int p = 0; p < 4; p++){
    f4 a = hp[lane + 64*p], c = up[lane + 64*p];
    acc += a[0]*c[0] + a[1]*c[1] + a[2]*c[2] + a[3]*c[3];
  }
  #pragma unroll
  for (int off = 32; off > 0; off >>= 1) acc += __shfl_xor(acc, off, 64);
  if (!lane) cba[z*1152 + l] = (acc + bqbk[s])*0.03125f;
}

// meanH2[b*1024+d] = (1/1024) * sum_l H2T[b][d][l]
__global__ __launch_bounds__(256) void meanh2_k(const u16* __restrict__ H2T, float* __restrict__ mh){
  int row = blockIdx.x*4 + (threadIdx.x >> 6);
  int lane = threadIdx.x & 63;
  const u16* p = H2T + (size_t)row*1024 + lane*16;
  float s = 0.0f;
  #pragma unroll
  for (int j = 0; j < 16; j++) s += b2f(p[j]);
  #pragma unroll
  for (int off = 32; off > 0; off >>= 1) s += __shfl_xor(s, off, 64);
  if (lane == 0) mh[row] = s * 0.0009765625f;
}

// row softmax: bf16 scores + rel gather -> probs f32 (d_out) + bf16 attnP;
// a row's LAST active iter (iter == w-1) also writes its uniform tail slots w..7
__global__ __launch_bounds__(256) void softmax_k(const u16* __restrict__ scB, float* __restrict__ outF,
                                                 u16* __restrict__ attnP, const float* __restrict__ qrelb,
                                                 const int* __restrict__ cnt, const int* __restrict__ perm,
                                                 const int* __restrict__ spw, int iter){
  int z = blockIdx.x >> 10, c = blockIdx.x & 1023;
  int s = z >> 2, b = z & 3;
  if (c >= cnt[b*8 + iter]) return;
  int ro = perm[b*1024 + c];
  __shared__ float qr[33];
  __shared__ float red[8];
  if (threadIdx.x < 33) qr[threadIdx.x] = qrelb[((size_t)z*1024 + c)*33 + threadIdx.x];
  __syncthreads();
  const u16* sc = scB + ((size_t)z*1024 + c)*1024;
  float* po = outF + (size_t)s*33554432ull + (((size_t)(b*1024 + ro))*8 + (size_t)iter)*1024;
  u16* pr = attnP + ((size_t)z*1024 + c)*1024;
  int t = threadIdx.x;
  float v[4]; float mx = -1e30f;
  #pragma unroll
  for (int j = 0; j < 4; j++){
    int col = t + j*256;
    int d = col - ro; d = d < -16 ? -16 : (d > 16 ? 16 : d);
    v[j] = b2f(sc[col]) + qr[d + 16];
    mx = fmaxf(mx, v[j]);
  }
  #pragma unroll
  for (int off = 32; off > 0; off >>= 1) mx = fmaxf(mx, __shfl_xor(mx, off, 64));
  int wv = t >> 6, ln = t & 63;
  if (ln == 0) red[wv] = mx;
  __syncthreads();
  mx = fmaxf(fmaxf(red[0], red[1]), fmaxf(red[2], red[3]));
  float sm = 0.0f;
  #pragma unroll
  for (int j = 0; j < 4; j++){ v[j] = __expf(v[j] - mx); sm += v[j]; }
  #pragma unroll
  for (int off = 32; off > 0; off >>= 1) sm += __shfl_xor(sm, off, 64);
  if (ln == 0) red[4 + wv] = sm;
  __syncthreads();
  sm = red[4] + red[5] + red[6] + red[7];
  float inv = 1.0f / sm;
  #pragma unroll
  for (int j = 0; j < 4; j++){
    float pv = v[j] * inv;
    po[t + j*256] = pv;
    pr[t + j*256] = f2b(pv);
  }
  int w = spw[b*1024 + ro];
  if (iter == w - 1 && w < 8){
    f4 u = {0.0009765625f, 0.0009765625f, 0.0009765625f, 0.0009765625f};
    for (int j = 1; j <= 7 - iter; j++)
      ((f4*)(po + (size_t)j*1024))[t] = u;
  }
}

// ---------------- MFMA GEMM, 128x128 tile, BK=64, depth-2 counted-vmcnt + swizzle + setprio
// (round-10 proven structure: single MFMA block per step, no intra-step lgkm staging)
template<int MODE>
__global__ __launch_bounds__(256) void gemm_k(
    const u16* __restrict__ A_, const u16* __restrict__ B_,
    const u16* __restrict__ A2_, const u16* __restrict__ B2_,
    const float* __restrict__ e0, const float* __restrict__ e1,
    u16* __restrict__ outB, float* __restrict__ qrelb,
    const int* __restrict__ cnt, int iter)
{
  const int z = blockIdx.z;
  const int s = (MODE == 1) ? 0 : (z >> 2);
  const int b = (MODE == 1) ? z : (z & 3);
  const size_t LD = 1024*1024;
  const int bm = blockIdx.y*128, bn = blockIdx.x*128;

  int cntv = 1024;
  if constexpr (MODE == 2 || MODE == 4){
    cntv = cnt[b*8 + iter];
    if (bm >= cntv) return;
  }

  const u16 *A1, *B1, *A2, *B2;
  int lda1 = 1024, ldb1 = 1024, lda2 = 1024, ldb2 = 1024, K = 1024, K1 = 1024;

  if constexpr (MODE == 0){ A1 = A_ + (size_t)z*LD; B1 = B_ + (size_t)z*LD; A2=A1; B2=B1; }
  else if constexpr (MODE == 1){ A1 = A_ + 1024; lda1 = 2048; B1 = B_ + (size_t)z*LD; A2=A1; B2=B1; lda2=lda1; }
  else if constexpr (MODE == 2){
    A1 = A_ + (size_t)z*LD; B1 = B_ + (size_t)b*LD;
    A2 = A2_ + (size_t)z*LD; B2 = B2_; ldb2 = 2048;
    if (iter == 0){ K = 1024; K1 = 0; } else { K = 2048; K1 = 1024; }
  }
  else if constexpr (MODE == 3){ A1 = A_ + (size_t)b*LD; B1 = B_ + (size_t)s*LD; A2=A1; B2=B1; }
  else { A1 = A_ + (size_t)z*LD; B1 = B_ + (size_t)z*1179648; A2=A1; B2=B1; }

  // 2 bufs x [2 K-halves][128 rows][32 cols] bf16 = 2 x 16 KB per operand (64 KB total)
  __shared__ __align__(16) u16 lA[16384];
  __shared__ __align__(16) u16 lB[16384];
  const int tid = threadIdx.x, wv = tid >> 6, lane = tid & 63;
  const int wr = (wv >> 1)*64, wc = (wv & 1)*64;
  const int fr = lane & 15, kh = lane >> 4;
  const int stRow = (lane >> 2);
  // T2 swizzle both-sides (rule #21): 16B slot' = slot ^ ((row&3)^((row>>2)&3))
  const int ssw  = ((lane >> 2) & 3) ^ ((lane >> 4) & 3);
  const int stCe = ((lane & 3) ^ ssw)*8;
  const int fsw  = (fr & 3) ^ ((fr >> 2) & 3);
  const int rdSl = (kh ^ fsw)*8;

  auto stage = [&](int bufsel, int k0s){
    const u16 *As, *Bs; int kk, la, lb;
    if (k0s < K1){ As = A1; Bs = B1; kk = k0s; la = lda1; lb = ldb1; }
    else         { As = A2; Bs = B2; kk = k0s - K1; la = lda2; lb = ldb2; }
    #pragma unroll
    for (int c = 0; c < 4; c++){
      const int n = wv*4 + c;                 // chunk 0..15 (1KB each)
      const int h = n >> 3;
      const int rl = (n & 7)*16 + stRow;
      const int ke = kk + h*32 + stCe;
      gload16(As + (size_t)(bm + rl)*la + ke, (char*)lA + bufsel*16384 + n*1024);
      gload16(Bs + (size_t)(bn + rl)*lb + ke, (char*)lB + bufsel*16384 + n*1024);
    }
  };

  f4 acc[4][4];
  #pragma unroll
  for (int i = 0; i < 4; i++)
    #pragma unroll
    for (int j = 0; j < 4; j++)
      acc[i][j] = f4{0.f, 0.f, 0.f, 0.f};

  stage(0, 0);
  stage(1, 64);               // K >= 128 always here

  int cur = 0;
  for (int k0 = 0; k0 < K; k0 += 64){
    // stage(t) landed (8 own loads of stage(t+1) may remain in flight)
    if (k0 + 64 < K) asm volatile("s_waitcnt vmcnt(8)" ::: "memory");
    else             asm volatile("s_waitcnt vmcnt(0)" ::: "memory");
    __builtin_amdgcn_s_barrier();           // all waves' stage(t) visible
    asm volatile("" ::: "memory");
    const u16* bufA = lA + cur*8192;
    const u16* bufB = lB + cur*8192;
    bh8 af[2][4], bfr[2][4];
    #pragma unroll
    for (int h = 0; h < 2; h++){
      #pragma unroll
      for (int i = 0; i < 4; i++){
        af[h][i]  = *(const bh8*)&bufA[h*4096 + (wr + i*16 + fr)*32 + rdSl];
        bfr[h][i] = *(const bh8*)&bufB[h*4096 + (wc + i*16 + fr)*32 + rdSl];
      }
    }
    if (k0 + 128 < K){
      asm volatile("s_waitcnt lgkmcnt(0)" ::: "memory");   // my reads done
      __builtin_amdgcn_sched_barrier(0);
      __builtin_amdgcn_s_barrier();           // all waves done reading buf[cur]
      asm volatile("" ::: "memory");
      stage(cur, k0 + 128);                   // refill buf[cur] for step t+2
    }
    __builtin_amdgcn_s_setprio(1);
    #pragma unroll
    for (int h = 0; h < 2; h++)
      #pragma unroll
      for (int i = 0; i < 4; i++)
        #pragma unroll
        for (int j = 0; j < 4; j++)
          acc[i][j] = __builtin_amdgcn_mfma_f32_16x16x32_bf16(af[h][i], bfr[h][j], acc[i][j], 0, 0, 0);
    __builtin_amdgcn_s_setprio(0);
    cur ^= 1;
  }

  const int rw = (lane >> 4)*4, cl = lane & 15;
  #pragma unroll
  for (int i = 0; i < 4; i++){
    #pragma unroll
    for (int r = 0; r < 4; r++){
      const int row = bm + wr + i*16 + rw + r;
      if constexpr (MODE == 2 || MODE == 4){ if (row >= cntv) continue; }
      #pragma unroll
      for (int j = 0; j < 4; j++){
        const int col = bn + wc + j*16 + cl;
        float v = acc[i][j][r];
        if constexpr (MODE == 0 || MODE == 1){
          outB[(size_t)z*LD + (size_t)row*1024 + col] = f2b(v);
        } else if constexpr (MODE == 2){
          v += e0[col];
          if (e1) v += e1[b*1024 + col];
          v = fmaxf(v, 0.0f);
          outB[(size_t)z*LD + (size_t)row*1024 + col] = f2b(v);
        } else if constexpr (MODE == 3){
          outB[(size_t)z*1179648 + (size_t)row*1024 + col] = f2b((v + e0[s*1024 + col])*0.03125f);
        } else {
          v += e0[z*1152 + col];
          if (col < 1024){
            outB[((size_t)z*1024 + row)*1024 + col] = f2b(v);
          } else {
            int rr = col - 1024;
            if (rr < 33) qrelb[((size_t)z*1024 + row)*33 + rr] = v;
          }
        }
      }
    }
  }
}

// ---------------- host ----------------

extern "C" void kernel_launch(void* const* d_in, const int* in_sizes, int n_in,
                              void* d_out, int out_size, void* d_ws, size_t ws_size,
                              hipStream_t stream)
{
  const float* hid    = (const float*)d_in[0];
  const float* srch   = (const float*)d_in[1];
  const int*   spw    = (const int*)d_in[2];
  const float* wq_st  = (const float*)d_in[6];
  const float* bq_st  = (const float*)d_in[7];
  const float* wk_st  = (const float*)d_in[8];
  const float* bk_st  = (const float*)d_in[9];
  const float* rel_st = (const float*)d_in[10];
  const float* wq_ed  = (const float*)d_in[11];
  const float* bq_ed  = (const float*)d_in[12];
  const float* wk_ed  = (const float*)d_in[13];
  const float* bk_ed  = (const float*)d_in[14];
  const float* rel_ed = (const float*)d_in[15];
  const float* sp_w   = (const float*)d_in[16];
  const float* sp_b   = (const float*)d_in[17];
  float* out = (float*)d_out;

  const size_t LD = 1024*1024;
  char* p = (char*)d_ws;
  u16* hidB  = (u16*)p; p += 4*LD*2;
  u16* wqB   = (u16*)p; p += 2*LD*2;
  u16* wkB   = (u16*)p; p += 2*LD*2;
  u16* spwT  = (u16*)p; p += 2*LD*2;
  u16* WT    = (u16*)p; p += 2*LD*2;
  u16* H2T   = (u16*)p; p += 4*LD*2;
  u16* Mx    = (u16*)p; p += 8ull*1179648*2;      // 8 x [1152][1024]
  u16* attnP = (u16*)p; p += 8*LD*2;
  u16* hbufA = (u16*)p; p += 8*LD*2;
  u16* hbufB = (u16*)p; p += 8*LD*2;
  u16* scB   = (u16*)p; p += 8*LD*2;
  float* qrelb  = (float*)p; p += 8*1024*33*4;
  float* cba    = (float*)p; p += 8*1152*4;
  float* ubuf   = (float*)p; p += 2048*4;
  float* c0buf  = (float*)p; p += 2048*4;
  float* bqbk   = (float*)p; p += 64;
  float* meanH2 = (float*)p; p += 4*1024*4;
  int*   perm   = (int*)p;   p += 4*1024*4;
  int*   cnt    = (int*)p;   p += 1024;

  const dim3 t256(256);

  // --- precompute ---
  convall_k<<<32768, t256, 0, stream>>>(hid, wq_st, wq_ed, wk_st, wk_ed, hidB, wqB, wkB);
  sort_k<<<4, t256, 0, stream>>>(spw, perm, cnt, out + 67108864ull);
  gather_k<<<8192, t256, 0, stream>>>(srch, perm, hbufA);
  uniform0_k<<<4096, t256, 0, stream>>>(spw, out);
  trans_k<<<dim3(32,64), t256, 0, stream>>>(sp_w, spwT, 2048, 1024);
  wrt_k<<<264, t256, 0, stream>>>(wq_st, wq_ed, rel_st, rel_ed, Mx);
  dots_k<<<1041, t256, 0, stream>>>(wq_st, wq_ed, wk_st, wk_ed, bq_st, bq_ed, bk_st, bk_ed,
                                    rel_st, rel_ed, ubuf, c0buf, bqbk, cba);
  cba_k<<<2048, t256, 0, stream>>>(hid, ubuf, bqbk, cba);

  gemm_k<0><<<dim3(8,8,2), t256, 0, stream>>>(wqB, wkB, nullptr, nullptr, nullptr, nullptr,
                                              WT, nullptr, nullptr, 0);
  gemm_k<3><<<dim3(8,8,8), t256, 0, stream>>>(hidB, WT, nullptr, nullptr, c0buf, nullptr,
                                              Mx, nullptr, nullptr, 0);
  gemm_k<1><<<dim3(8,8,4), t256, 0, stream>>>(spwT, hidB, nullptr, nullptr, nullptr, nullptr,
                                              H2T, nullptr, nullptr, 0);
  meanh2_k<<<1024, t256, 0, stream>>>(H2T, meanH2);

  u16* hp = hbufA; u16* hn = hbufB;
  for (int i = 0; i < 8; i++){
    gemm_k<2><<<dim3(8,8,8), t256, 0, stream>>>(attnP, H2T, hp, spwT, sp_b,
                                                (i == 0) ? meanH2 : nullptr,
                                                hn, nullptr, cnt, i);
    gemm_k<4><<<dim3(9,8,8), t256, 0, stream>>>(hn, Mx, nullptr, nullptr, cba, nullptr,
                                                scB, qrelb, cnt, i);
    softmax_k<<<8192, t256, 0, stream>>>(scB, out, attnP, qrelb, cnt, perm, spw, i);
    u16* tmp = hp; hp = hn; hn = tmp;
  }
}

// Round 13
// 909.047 us; speedup vs baseline: 1.0622x; 1.0111x over previous
//
#include <hip/hip_runtime.h>

typedef unsigned short u16;
typedef __attribute__((ext_vector_type(8))) short bh8;
typedef __attribute__((ext_vector_type(4))) float f4;

__device__ __forceinline__ u16 f2b(float x){
  union { float f; unsigned u; } c; c.f = x;
  unsigned r = (c.u + 0x7FFFu + ((c.u >> 16) & 1u)) >> 16;
  return (u16)r;
}
__device__ __forceinline__ float b2f(u16 h){
  union { unsigned u; float f; } c; c.u = ((unsigned)h) << 16; return c.f;
}
__device__ __forceinline__ void gload16(const void* g, void* l){
  __builtin_amdgcn_global_load_lds((const __attribute__((address_space(1))) void*)g,
                                   (__attribute__((address_space(3))) void*)l, 16, 0, 0);
}

// ---------------- small utility kernels ----------------

__global__ __launch_bounds__(256) void convall_k(const float* __restrict__ hid,
                                                 const float* __restrict__ wq0, const float* __restrict__ wq1,
                                                 const float* __restrict__ wk0, const float* __restrict__ wk1,
                                                 u16* __restrict__ hidB, u16* __restrict__ wqB, u16* __restrict__ wkB){
  long i = (long)blockIdx.x*256 + threadIdx.x;
  const float* src; u16* dst; long off;
  if      (i < 4194304L){ src = hid; dst = hidB;           off = i; }
  else if (i < 5242880L){ src = wq0; dst = wqB;            off = i - 4194304L; }
  else if (i < 6291456L){ src = wq1; dst = wqB + 1048576;  off = i - 5242880L; }
  else if (i < 7340032L){ src = wk0; dst = wkB;            off = i - 6291456L; }
  else                  { src = wk1; dst = wkB + 1048576;  off = i - 7340032L; }
  dst[off] = f2b(src[off]);
}

// uniform prefill ONLY for rows with width==0 (never touched by softmax); both streams
__global__ __launch_bounds__(256) void uniform0_k(const int* __restrict__ spw, float* __restrict__ out){
  int bl = blockIdx.x;              // b*1024 + l, 4096 blocks
  if (spw[bl] != 0) return;
  f4 t = {0.0009765625f, 0.0009765625f, 0.0009765625f, 0.0009765625f};
  float* b0 = out + (size_t)bl*8192;
  float* b1 = out + 33554432ull + (size_t)bl*8192;
  #pragma unroll
  for (int i = 0; i < 8; i++){
    ((f4*)(b0 + (size_t)i*1024))[threadIdx.x] = t;
    ((f4*)(b1 + (size_t)i*1024))[threadIdx.x] = t;
  }
}

// transpose [R][C] f32 -> [C][R] bf16
__global__ __launch_bounds__(256) void trans_k(const float* __restrict__ in, u16* __restrict__ out,
                                               int R, int C){
  __shared__ u16 t[32][33];
  int bx = blockIdx.x*32, by = blockIdx.y*32;
  int tx = threadIdx.x & 31, ty = threadIdx.x >> 5;
  #pragma unroll
  for (int j = 0; j < 32; j += 8) t[ty+j][tx] = f2b(in[(size_t)(by+ty+j)*C + bx+tx]);
  __syncthreads();
  #pragma unroll
  for (int j = 0; j < 32; j += 8) out[(size_t)(bx+ty+j)*R + by+tx] = t[tx][ty+j];
}

// counting sort rows per batch by width descending + emit masks output
__global__ __launch_bounds__(256) void sort_k(const int* __restrict__ spw, int* __restrict__ perm,
                                              int* __restrict__ cnt, float* __restrict__ mout){
  int b = blockIdx.x, t = threadIdx.x;
  __shared__ int hist[9], start[9];
  if (t < 9) hist[t] = 0;
  __syncthreads();
  for (int l = t; l < 1024; l += 256) atomicAdd(&hist[spw[b*1024 + l]], 1);
  __syncthreads();
  if (t == 0){
    int acc = 0;
    for (int w = 8; w >= 0; w--){ start[w] = acc; acc += hist[w]; }
  }
  __syncthreads();
  if (t < 8) cnt[b*8 + t] = start[t];
  __syncthreads();
  for (int l = t; l < 1024; l += 256){
    int w = spw[b*1024 + l];
    float* mo = mout + ((size_t)b*1024 + l)*8;
    #pragma unroll
    for (int i = 0; i < 8; i++) mo[i] = (i < w) ? 1.0f : 0.0f;
    int pos = atomicAdd(&start[w], 1);
    perm[b*1024 + pos] = l;
  }
}

// gather compacted srch rows -> hbufA[z], z=0..3 only (st/ed identical at i=0)
__global__ __launch_bounds__(256) void gather_k(const float* __restrict__ srch, const int* __restrict__ perm,
                                                u16* __restrict__ hb){
  int blk = blockIdx.x;             // z*1024 + c, 4096 blocks
  int z = blk >> 10, c = blk & 1023;
  int ro = perm[z*1024 + c];
  const float* src = srch + ((size_t)z*1024 + ro)*1024;
  u16* dst = hb + ((size_t)z*1024 + c)*1024;
  for (int d = threadIdx.x; d < 1024; d += 256) dst[d] = f2b(src[d]);
}

// Mx rel rows: Mx[z][1024+r][e] = (1/32)*sum_k wq_s[e][k]*rel_s[r][k], written to all 4 b of s
__global__ __launch_bounds__(256) void wrt_k(const float* __restrict__ wq0, const float* __restrict__ wq1,
                                             const float* __restrict__ rel0, const float* __restrict__ rel1,
                                             u16* __restrict__ Mx){
  long idx = (long)blockIdx.x*256 + threadIdx.x;
  if (idx >= 2L*33*1024) return;
  int s = idx >= 33*1024; long loc = idx - (s ? 33*1024 : 0);
  int r = (int)(loc >> 10), e = (int)(loc & 1023);
  const float* wqrow = (s ? wq1 : wq0) + (size_t)e*1024;
  const float* rel = (s ? rel1 : rel0) + (size_t)r*1024;
  float acc = 0.0f;
  #pragma unroll 4
  for (int k = 0; k < 1024; k++) acc += wqrow[k]*rel[k];
  u16 v = f2b(acc*0.03125f);
  size_t o = (size_t)(1024 + r)*1024 + e;
  #pragma unroll
  for (int b = 0; b < 4; b++)
    Mx[(size_t)(s*4 + b)*1179648 + o] = v;
}

// merged dot products (see round-4 comment)
__global__ __launch_bounds__(256) void dots_k(const float* __restrict__ wq0, const float* __restrict__ wq1,
                                              const float* __restrict__ wk0, const float* __restrict__ wk1,
                                              const float* __restrict__ bq0, const float* __restrict__ bq1,
                                              const float* __restrict__ bk0, const float* __restrict__ bk1,
                                              const float* __restrict__ rel0, const float* __restrict__ rel1,
                                              float* __restrict__ ubuf, float* __restrict__ c0buf,
                                              float* __restrict__ bqbk, float* __restrict__ cba){
  int row = blockIdx.x*4 + (threadIdx.x >> 6);
  int lane = threadIdx.x & 63;
  if (row >= 4164) return;
  const float *a, *v;
  int kind = 0, oi = 0, br_s = 0, br_r = 0;
  if      (row < 1024){ a = wk0 + (size_t)row*1024; v = bq0; oi = row; }
  else if (row < 2048){ a = wk1 + (size_t)(row-1024)*1024; v = bq1; oi = row; }
  else if (row < 3072){ a = wq0 + (size_t)(row-2048)*1024; v = bk0; kind = 1; oi = row-2048; }
  else if (row < 4096){ a = wq1 + (size_t)(row-3072)*1024; v = bk1; kind = 1; oi = row-3072+1024; }
  else if (row < 4162){ int idx = row-4096; br_s = idx/33; br_r = idx%33;
                        a = (br_s ? rel1 : rel0) + (size_t)br_r*1024; v = br_s ? bq1 : bq0; kind = 2; }
  else                { int s2 = row-4162; a = s2 ? bq1 : bq0; v = s2 ? bk1 : bk0; kind = 3; oi = s2; }
  const f4* ap = (const f4*)a;
  const f4* vp = (const f4*)v;
  float acc = 0.0f;
  #pragma unroll
  for (int p = 0; p < 4; p++){
    f4 x = ap[lane + 64*p], y = vp[lane + 64*p];
    acc += x[0]*y[0] + x[1]*y[1] + x[2]*y[2] + x[3]*y[3];
  }
  #pragma unroll
  for (int off = 32; off > 0; off >>= 1) acc += __shfl_xor(acc, off, 64);
  if (lane == 0){
    if (kind == 0) ubuf[oi] = acc;
    else if (kind == 1) c0buf[oi] = acc;
    else if (kind == 2){
      float w = acc*0.03125f;
      for (int b = 0; b < 4; b++) cba[(br_s*4 + b)*1152 + 1024 + br_r] = w;
    } else bqbk[oi] = acc;
  }
}

// cba[z*1152+l] = (hid[b][l].u_s + bqbk_s)/32
__global__ __launch_bounds__(256) void cba_k(const float* __restrict__ hid, const float* __restrict__ u,
                                             const float* __restrict__ bqbk, float* __restrict__ cba){
  int row = blockIdx.x*4 + (threadIdx.x >> 6);  // z*1024+l
  int lane = threadIdx.x & 63;
  int z = row >> 10, l = row & 1023, b = z & 3, s = z >> 2;
  const f4* hp = (const f4*)(hid + ((size_t)b*1024 + l)*1024);
  const f4* up = (const f4*)(u + s*1024);
  float acc = 0.0f;
  #pragma unroll
  for (int p = 0; p < 4; p++){
    f4 a = hp[lane + 64*p], c = up[lane + 64*p];
    acc += a[0]*c[0] + a[1]*c[1] + a[2]*c[2] + a[3]*c[3];
  }
  #pragma unroll
  for (int off = 32; off > 0; off >>= 1) acc += __shfl_xor(acc, off, 64);
  if (!lane) cba[z*1152 + l] = (acc + bqbk[s])*0.03125f;
}

// meanH2[b*1024+d] = (1/1024) * sum_l H2T[b][d][l]
__global__ __launch_bounds__(256) void meanh2_k(const u16* __restrict__ H2T, float* __restrict__ mh){
  int row = blockIdx.x*4 + (threadIdx.x >> 6);
  int lane = threadIdx.x & 63;
  const u16* p = H2T + (size_t)row*1024 + lane*16;
  float s = 0.0f;
  #pragma unroll
  for (int j = 0; j < 16; j++) s += b2f(p[j]);
  #pragma unroll
  for (int off = 32; off > 0; off >>= 1) s += __shfl_xor(s, off, 64);
  if (lane == 0) mh[row] = s * 0.0009765625f;
}

// row softmax: bf16 scores + rel gather -> probs f32 (d_out) + bf16 attnP;
// a row's LAST active iter (iter == w-1) also writes its uniform tail slots w..7
__global__ __launch_bounds__(256) void softmax_k(const u16* __restrict__ scB, float* __restrict__ outF,
                                                 u16* __restrict__ attnP, const float* __restrict__ qrelb,
                                                 const int* __restrict__ cnt, const int* __restrict__ perm,
                                                 const int* __restrict__ spw, int iter){
  int z = blockIdx.x >> 10, c = blockIdx.x & 1023;
  int s = z >> 2, b = z & 3;
  if (c >= cnt[b*8 + iter]) return;
  int ro = perm[b*1024 + c];
  __shared__ float qr[33];
  __shared__ float red[8];
  if (threadIdx.x < 33) qr[threadIdx.x] = qrelb[((size_t)z*1024 + c)*33 + threadIdx.x];
  __syncthreads();
  const u16* sc = scB + ((size_t)z*1024 + c)*1024;
  float* po = outF + (size_t)s*33554432ull + (((size_t)(b*1024 + ro))*8 + (size_t)iter)*1024;
  u16* pr = attnP + ((size_t)z*1024 + c)*1024;
  int t = threadIdx.x;
  float v[4]; float mx = -1e30f;
  #pragma unroll
  for (int j = 0; j < 4; j++){
    int col = t + j*256;
    int d = col - ro; d = d < -16 ? -16 : (d > 16 ? 16 : d);
    v[j] = b2f(sc[col]) + qr[d + 16];
    mx = fmaxf(mx, v[j]);
  }
  #pragma unroll
  for (int off = 32; off > 0; off >>= 1) mx = fmaxf(mx, __shfl_xor(mx, off, 64));
  int wv = t >> 6, ln = t & 63;
  if (ln == 0) red[wv] = mx;
  __syncthreads();
  mx = fmaxf(fmaxf(red[0], red[1]), fmaxf(red[2], red[3]));
  float sm = 0.0f;
  #pragma unroll
  for (int j = 0; j < 4; j++){ v[j] = __expf(v[j] - mx); sm += v[j]; }
  #pragma unroll
  for (int off = 32; off > 0; off >>= 1) sm += __shfl_xor(sm, off, 64);
  if (ln == 0) red[4 + wv] = sm;
  __syncthreads();
  sm = red[4] + red[5] + red[6] + red[7];
  float inv = 1.0f / sm;
  #pragma unroll
  for (int j = 0; j < 4; j++){
    float pv = v[j] * inv;
    po[t + j*256] = pv;
    pr[t + j*256] = f2b(pv);
  }
  int w = spw[b*1024 + ro];
  if (iter == w - 1 && w < 8){
    f4 u = {0.0009765625f, 0.0009765625f, 0.0009765625f, 0.0009765625f};
    for (int j = 1; j <= 7 - iter; j++)
      ((f4*)(po + (size_t)j*1024))[t] = u;
  }
}

// ---------------- MFMA GEMM, 128x128 tile, BK=64, depth-2 counted-vmcnt + swizzle + setprio
// MODE 0: WT[s]  = wqB[s] @ wkB[s]^T                              (grid 8,8,2)
// MODE 2: hn[z]  = relu(attnP[z]@H2T + hp[z&am]@W1 + sp_b (+mh))  compacted
// MODE 4: sc     = hn[z&am] @ Mx[z]^T (+cba) -> scB / qrelb       compacted
// MODE 5: z<8 -> Mx[z] = (hidB[b]@WT[s]^T + c0)/32 ; z>=8 -> H2T[z-8] = W2^T @ hidB
template<int MODE>
__global__ __launch_bounds__(256) void gemm_k(
    const u16* __restrict__ A_, const u16* __restrict__ B_,
    const u16* __restrict__ A2_, const u16* __restrict__ B2_,
    const float* __restrict__ e0, const float* __restrict__ e1,
    u16* __restrict__ outB, u16* __restrict__ outB2, float* __restrict__ qrelb,
    const int* __restrict__ cnt, int iter, int azmask)
{
  const int z = blockIdx.z;
  const size_t LD = 1024*1024;
  const int bm = blockIdx.y*128, bn = blockIdx.x*128;
  int s = z >> 2, b = z & 3;
  bool m5h2 = false;                 // MODE5: H2T sub-job
  if constexpr (MODE == 5){ if (z >= 8){ m5h2 = true; b = z - 8; s = 0; } }

  int cntv = 1024;
  if constexpr (MODE == 2 || MODE == 4){
    cntv = cnt[b*8 + iter];
    if (bm >= cntv) return;
  }

  const u16 *A1, *B1, *A2, *B2;
  int lda1 = 1024, ldb1 = 1024, lda2 = 1024, ldb2 = 1024, K = 1024, K1 = 1024;

  if constexpr (MODE == 0){ A1 = A_ + (size_t)z*LD; B1 = B_ + (size_t)z*LD; A2=A1; B2=B1; }
  else if constexpr (MODE == 2){
    A1 = A_ + (size_t)z*LD; B1 = B_ + (size_t)b*LD;
    A2 = A2_ + (size_t)(z & azmask)*LD; B2 = B2_; ldb2 = 2048;
    if (iter == 0){ K = 1024; K1 = 0; } else { K = 2048; K1 = 1024; }
  }
  else if constexpr (MODE == 4){ A1 = A_ + (size_t)(z & azmask)*LD; B1 = B_ + (size_t)z*1179648; A2=A1; B2=B1; }
  else { // MODE 5
    if (!m5h2){ A1 = A_ + (size_t)b*LD; B1 = B_ + (size_t)s*LD; }
    else      { A1 = A2_ + 1024; lda1 = 2048; B1 = B2_ + (size_t)b*LD; }
    A2=A1; B2=B1; lda2=lda1;
  }

  // 2 bufs x [2 K-halves][128 rows][32 cols] bf16 = 2 x 16 KB per operand (64 KB total)
  __shared__ __align__(16) u16 lA[16384];
  __shared__ __align__(16) u16 lB[16384];
  const int tid = threadIdx.x, wv = tid >> 6, lane = tid & 63;
  const int wr = (wv >> 1)*64, wc = (wv & 1)*64;
  const int fr = lane & 15, kh = lane >> 4;
  const int stRow = (lane >> 2);
  // T2 swizzle both-sides (rule #21): 16B slot' = slot ^ ((row&3)^((row>>2)&3))
  const int ssw  = ((lane >> 2) & 3) ^ ((lane >> 4) & 3);
  const int stCe = ((lane & 3) ^ ssw)*8;
  const int fsw  = (fr & 3) ^ ((fr >> 2) & 3);
  const int rdSl = (kh ^ fsw)*8;

  auto stage = [&](int bufsel, int k0s){
    const u16 *As, *Bs; int kk, la, lb;
    if (k0s < K1){ As = A1; Bs = B1; kk = k0s; la = lda1; lb = ldb1; }
    else         { As = A2; Bs = B2; kk = k0s - K1; la = lda2; lb = ldb2; }
    #pragma unroll
    for (int c = 0; c < 4; c++){
      const int n = wv*4 + c;                 // chunk 0..15 (1KB each)
      const int h = n >> 3;
      const int rl = (n & 7)*16 + stRow;
      const int ke = kk + h*32 + stCe;
      gload16(As + (size_t)(bm + rl)*la + ke, (char*)lA + bufsel*16384 + n*1024);
      gload16(Bs + (size_t)(bn + rl)*lb + ke, (char*)lB + bufsel*16384 + n*1024);
    }
  };

  f4 acc[4][4];
  #pragma unroll
  for (int i = 0; i < 4; i++)
    #pragma unroll
    for (int j = 0; j < 4; j++)
      acc[i][j] = f4{0.f, 0.f, 0.f, 0.f};

  stage(0, 0);
  stage(1, 64);               // K >= 128 always here

  int cur = 0;
  for (int k0 = 0; k0 < K; k0 += 64){
    // stage(t) landed (8 own loads of stage(t+1) may remain in flight)
    if (k0 + 64 < K) asm volatile("s_waitcnt vmcnt(8)" ::: "memory");
    else             asm volatile("s_waitcnt vmcnt(0)" ::: "memory");
    __builtin_amdgcn_s_barrier();           // all waves' stage(t) visible
    asm volatile("" ::: "memory");
    const u16* bufA = lA + cur*8192;
    const u16* bufB = lB + cur*8192;
    bh8 af[2][4], bfr[2][4];
    #pragma unroll
    for (int h = 0; h < 2; h++){
      #pragma unroll
      for (int i = 0; i < 4; i++){
        af[h][i]  = *(const bh8*)&bufA[h*4096 + (wr + i*16 + fr)*32 + rdSl];
        bfr[h][i] = *(const bh8*)&bufB[h*4096 + (wc + i*16 + fr)*32 + rdSl];
      }
    }
    if (k0 + 128 < K){
      asm volatile("s_waitcnt lgkmcnt(0)" ::: "memory");   // my reads done
      __builtin_amdgcn_sched_barrier(0);
      __builtin_amdgcn_s_barrier();           // all waves done reading buf[cur]
      asm volatile("" ::: "memory");
      stage(cur, k0 + 128);                   // refill buf[cur] for step t+2
    }
    __builtin_amdgcn_s_setprio(1);
    #pragma unroll
    for (int h = 0; h < 2; h++)
      #pragma unroll
      for (int i = 0; i < 4; i++)
        #pragma unroll
        for (int j = 0; j < 4; j++)
          acc[i][j] = __builtin_amdgcn_mfma_f32_16x16x32_bf16(af[h][i], bfr[h][j], acc[i][j], 0, 0, 0);
    __builtin_amdgcn_s_setprio(0);
    cur ^= 1;
  }

  const int rw = (lane >> 4)*4, cl = lane & 15;
  #pragma unroll
  for (int i = 0; i < 4; i++){
    #pragma unroll
    for (int r = 0; r < 4; r++){
      const int row = bm + wr + i*16 + rw + r;
      if constexpr (MODE == 2 || MODE == 4){ if (row >= cntv) continue; }
      #pragma unroll
      for (int j = 0; j < 4; j++){
        const int col = bn + wc + j*16 + cl;
        float v = acc[i][j][r];
        if constexpr (MODE == 0){
          outB[(size_t)z*LD + (size_t)row*1024 + col] = f2b(v);
        } else if constexpr (MODE == 2){
          v += e0[col];
          if (e1) v += e1[b*1024 + col];
          v = fmaxf(v, 0.0f);
          outB[(size_t)z*LD + (size_t)row*1024 + col] = f2b(v);
        } else if constexpr (MODE == 5){
          if (!m5h2)
            outB[(size_t)z*1179648 + (size_t)row*1024 + col] = f2b((v + e0[s*1024 + col])*0.03125f);
          else
            outB2[(size_t)b*LD + (size_t)row*1024 + col] = f2b(v);
        } else {
          v += e0[z*1152 + col];
          if (col < 1024){
            outB[((size_t)z*1024 + row)*1024 + col] = f2b(v);
          } else {
            int rr = col - 1024;
            if (rr < 33) qrelb[((size_t)z*1024 + row)*33 + rr] = v;
          }
        }
      }
    }
  }
}

// ---------------- host ----------------

extern "C" void kernel_launch(void* const* d_in, const int* in_sizes, int n_in,
                              void* d_out, int out_size, void* d_ws, size_t ws_size,
                              hipStream_t stream)
{
  const float* hid    = (const float*)d_in[0];
  const float* srch   = (const float*)d_in[1];
  const int*   spw    = (const int*)d_in[2];
  const float* wq_st  = (const float*)d_in[6];
  const float* bq_st  = (const float*)d_in[7];
  const float* wk_st  = (const float*)d_in[8];
  const float* bk_st  = (const float*)d_in[9];
  const float* rel_st = (const float*)d_in[10];
  const float* wq_ed  = (const float*)d_in[11];
  const float* bq_ed  = (const float*)d_in[12];
  const float* wk_ed  = (const float*)d_in[13];
  const float* bk_ed  = (const float*)d_in[14];
  const float* rel_ed = (const float*)d_in[15];
  const float* sp_w   = (const float*)d_in[16];
  const float* sp_b   = (const float*)d_in[17];
  float* out = (float*)d_out;

  const size_t LD = 1024*1024;
  char* p = (char*)d_ws;
  u16* hidB  = (u16*)p; p += 4*LD*2;
  u16* wqB   = (u16*)p; p += 2*LD*2;
  u16* wkB   = (u16*)p; p += 2*LD*2;
  u16* spwT  = (u16*)p; p += 2*LD*2;
  u16* WT    = (u16*)p; p += 2*LD*2;
  u16* H2T   = (u16*)p; p += 4*LD*2;
  u16* Mx    = (u16*)p; p += 8ull*1179648*2;      // 8 x [1152][1024]
  u16* attnP = (u16*)p; p += 8*LD*2;
  u16* hbufA = (u16*)p; p += 8*LD*2;
  u16* hbufB = (u16*)p; p += 8*LD*2;
  u16* scB   = (u16*)p; p += 8*LD*2;
  float* qrelb  = (float*)p; p += 8*1024*33*4;
  float* cba    = (float*)p; p += 8*1152*4;
  float* ubuf   = (float*)p; p += 2048*4;
  float* c0buf  = (float*)p; p += 2048*4;
  float* bqbk   = (float*)p; p += 64;
  float* meanH2 = (float*)p; p += 4*1024*4;
  int*   perm   = (int*)p;   p += 4*1024*4;
  int*   cnt    = (int*)p;   p += 1024;

  const dim3 t256(256);

  // --- precompute ---
  convall_k<<<32768, t256, 0, stream>>>(hid, wq_st, wq_ed, wk_st, wk_ed, hidB, wqB, wkB);
  sort_k<<<4, t256, 0, stream>>>(spw, perm, cnt, out + 67108864ull);
  gather_k<<<4096, t256, 0, stream>>>(srch, perm, hbufA);
  uniform0_k<<<4096, t256, 0, stream>>>(spw, out);
  trans_k<<<dim3(32,64), t256, 0, stream>>>(sp_w, spwT, 2048, 1024);
  wrt_k<<<264, t256, 0, stream>>>(wq_st, wq_ed, rel_st, rel_ed, Mx);
  dots_k<<<1041, t256, 0, stream>>>(wq_st, wq_ed, wk_st, wk_ed, bq_st, bq_ed, bk_st, bk_ed,
                                    rel_st, rel_ed, ubuf, c0buf, bqbk, cba);
  cba_k<<<2048, t256, 0, stream>>>(hid, ubuf, bqbk, cba);

  gemm_k<0><<<dim3(8,8,2), t256, 0, stream>>>(wqB, wkB, nullptr, nullptr, nullptr, nullptr,
                                              WT, nullptr, nullptr, nullptr, 0, 7);
  // merged: z<8 -> Mx (hidB@WT^T), z>=8 -> H2T (spwT lower half @ hidB)
  gemm_k<5><<<dim3(8,8,12), t256, 0, stream>>>(hidB, WT, spwT, hidB, c0buf, nullptr,
                                               Mx, H2T, nullptr, nullptr, 0, 7);
  meanh2_k<<<1024, t256, 0, stream>>>(H2T, meanH2);

  u16* hp = hbufA; u16* hn = hbufB;
  for (int i = 0; i < 8; i++){
    // i==0: hn identical for st/ed (no attnP term) -> compute z=0..3 only
    int g2z = (i == 0) ? 4 : 8;
    int am2 = (i <= 1) ? 3 : 7;   // hp buffer has 4 z-copies at i=0 (gather) and i=1 (hn from i=0)
    gemm_k<2><<<dim3(8,8,g2z), t256, 0, stream>>>(attnP, H2T, hp, spwT, sp_b,
                                                  (i == 0) ? meanH2 : nullptr,
                                                  hn, nullptr, nullptr, cnt, i, am2);
    int am4 = (i == 0) ? 3 : 7;
    gemm_k<4><<<dim3(9,8,8), t256, 0, stream>>>(hn, Mx, nullptr, nullptr, cba, nullptr,
                                                scB, nullptr, qrelb, cnt, i, am4);
    softmax_k<<<8192, t256, 0, stream>>>(scB, out, attnP, qrelb, cnt, perm, spw, i);
    u16* tmp = hp; hp = hn; hn = tmp;
  }
}

// Round 14
// 820.452 us; speedup vs baseline: 1.1769x; 1.1080x over previous
//
#include <hip/hip_runtime.h>

typedef unsigned short u16;
typedef __attribute__((ext_vector_type(8))) short bh8;
typedef __attribute__((ext_vector_type(4))) float f4;

__device__ __forceinline__ u16 f2b(float x){
  union { float f; unsigned u; } c; c.f = x;
  unsigned r = (c.u + 0x7FFFu + ((c.u >> 16) & 1u)) >> 16;
  return (u16)r;
}
__device__ __forceinline__ float b2f(u16 h){
  union { unsigned u; float f; } c; c.u = ((unsigned)h) << 16; return c.f;
}
__device__ __forceinline__ void gload16(const void* g, void* l){
  __builtin_amdgcn_global_load_lds((const __attribute__((address_space(1))) void*)g,
                                   (__attribute__((address_space(3))) void*)l, 16, 0, 0);
}

// ---------------- small utility kernels ----------------

// vectorized bf16 convert: hid, wq x2, wk x2, rel x2 (f4 -> ushort4)
__global__ __launch_bounds__(256) void convall_k(const float* __restrict__ hid,
                                                 const float* __restrict__ wq0, const float* __restrict__ wq1,
                                                 const float* __restrict__ wk0, const float* __restrict__ wk1,
                                                 const float* __restrict__ rel0, const float* __restrict__ rel1,
                                                 u16* __restrict__ hidB, u16* __restrict__ wqB,
                                                 u16* __restrict__ wkB, u16* __restrict__ relB){
  long g = (long)blockIdx.x*256 + threadIdx.x;   // group of 4 elems
  if (g >= 2114048L) return;
  const float* src; u16* dst; long off;
  if      (g < 1048576L){ src = hid;  dst = hidB;           off = g; }
  else if (g < 1310720L){ src = wq0;  dst = wqB;            off = g - 1048576L; }
  else if (g < 1572864L){ src = wq1;  dst = wqB + 1048576;  off = g - 1310720L; }
  else if (g < 1835008L){ src = wk0;  dst = wkB;            off = g - 1572864L; }
  else if (g < 2097152L){ src = wk1;  dst = wkB + 1048576;  off = g - 1835008L; }
  else if (g < 2105600L){ src = rel0; dst = relB;           off = g - 2097152L; }
  else                  { src = rel1; dst = relB + 131072;  off = g - 2105600L; }
  f4 v = *(const f4*)(src + off*4);
  ushort4 pk = make_ushort4(f2b(v[0]), f2b(v[1]), f2b(v[2]), f2b(v[3]));
  *(ushort4*)(dst + off*4) = pk;
}

// uniform prefill ONLY for rows with width==0 (never touched by softmax); both streams
__global__ __launch_bounds__(256) void uniform0_k(const int* __restrict__ spw, float* __restrict__ out){
  int bl = blockIdx.x;              // b*1024 + l, 4096 blocks
  if (spw[bl] != 0) return;
  f4 t = {0.0009765625f, 0.0009765625f, 0.0009765625f, 0.0009765625f};
  float* b0 = out + (size_t)bl*8192;
  float* b1 = out + 33554432ull + (size_t)bl*8192;
  #pragma unroll
  for (int i = 0; i < 8; i++){
    ((f4*)(b0 + (size_t)i*1024))[threadIdx.x] = t;
    ((f4*)(b1 + (size_t)i*1024))[threadIdx.x] = t;
  }
}

// transpose [R][C] f32 -> [C][R] bf16
__global__ __launch_bounds__(256) void trans_k(const float* __restrict__ in, u16* __restrict__ out,
                                               int R, int C){
  __shared__ u16 t[32][33];
  int bx = blockIdx.x*32, by = blockIdx.y*32;
  int tx = threadIdx.x & 31, ty = threadIdx.x >> 5;
  #pragma unroll
  for (int j = 0; j < 32; j += 8) t[ty+j][tx] = f2b(in[(size_t)(by+ty+j)*C + bx+tx]);
  __syncthreads();
  #pragma unroll
  for (int j = 0; j < 32; j += 8) out[(size_t)(bx+ty+j)*R + by+tx] = t[tx][ty+j];
}

// counting sort rows per batch by width descending + emit masks output
__global__ __launch_bounds__(256) void sort_k(const int* __restrict__ spw, int* __restrict__ perm,
                                              int* __restrict__ cnt, float* __restrict__ mout){
  int b = blockIdx.x, t = threadIdx.x;
  __shared__ int hist[9], start[9];
  if (t < 9) hist[t] = 0;
  __syncthreads();
  for (int l = t; l < 1024; l += 256) atomicAdd(&hist[spw[b*1024 + l]], 1);
  __syncthreads();
  if (t == 0){
    int acc = 0;
    for (int w = 8; w >= 0; w--){ start[w] = acc; acc += hist[w]; }
  }
  __syncthreads();
  if (t < 8) cnt[b*8 + t] = start[t];
  __syncthreads();
  for (int l = t; l < 1024; l += 256){
    int w = spw[b*1024 + l];
    float* mo = mout + ((size_t)b*1024 + l)*8;
    #pragma unroll
    for (int i = 0; i < 8; i++) mo[i] = (i < w) ? 1.0f : 0.0f;
    int pos = atomicAdd(&start[w], 1);
    perm[b*1024 + pos] = l;
  }
}

// gather compacted srch rows -> hbufA[z], z=0..3 only (st/ed identical at i=0)
__global__ __launch_bounds__(256) void gather_k(const float* __restrict__ srch, const int* __restrict__ perm,
                                                u16* __restrict__ hb){
  int blk = blockIdx.x;             // z*1024 + c, 4096 blocks
  int z = blk >> 10, c = blk & 1023;
  int ro = perm[z*1024 + c];
  const float* src = srch + ((size_t)z*1024 + ro)*1024;
  u16* dst = hb + ((size_t)z*1024 + c)*1024;
  for (int d = threadIdx.x; d < 1024; d += 256) dst[d] = f2b(src[d]);
}

// merged dot products (see round-4 comment)
__global__ __launch_bounds__(256) void dots_k(const float* __restrict__ wq0, const float* __restrict__ wq1,
                                              const float* __restrict__ wk0, const float* __restrict__ wk1,
                                              const float* __restrict__ bq0, const float* __restrict__ bq1,
                                              const float* __restrict__ bk0, const float* __restrict__ bk1,
                                              const float* __restrict__ rel0, const float* __restrict__ rel1,
                                              float* __restrict__ ubuf, float* __restrict__ c0buf,
                                              float* __restrict__ bqbk, float* __restrict__ cba){
  int row = blockIdx.x*4 + (threadIdx.x >> 6);
  int lane = threadIdx.x & 63;
  if (row >= 4164) return;
  const float *a, *v;
  int kind = 0, oi = 0, br_s = 0, br_r = 0;
  if      (row < 1024){ a = wk0 + (size_t)row*1024; v = bq0; oi = row; }
  else if (row < 2048){ a = wk1 + (size_t)(row-1024)*1024; v = bq1; oi = row; }
  else if (row < 3072){ a = wq0 + (size_t)(row-2048)*1024; v = bk0; kind = 1; oi = row-2048; }
  else if (row < 4096){ a = wq1 + (size_t)(row-3072)*1024; v = bk1; kind = 1; oi = row-3072+1024; }
  else if (row < 4162){ int idx = row-4096; br_s = idx/33; br_r = idx%33;
                        a = (br_s ? rel1 : rel0) + (size_t)br_r*1024; v = br_s ? bq1 : bq0; kind = 2; }
  else                { int s2 = row-4162; a = s2 ? bq1 : bq0; v = s2 ? bk1 : bk0; kind = 3; oi = s2; }
  const f4* ap = (const f4*)a;
  const f4* vp = (const f4*)v;
  float acc = 0.0f;
  #pragma unroll
  for (int p = 0; p < 4; p++){
    f4 x = ap[lane + 64*p], y = vp[lane + 64*p];
    acc += x[0]*y[0] + x[1]*y[1] + x[2]*y[2] + x[3]*y[3];
  }
  #pragma unroll
  for (int off = 32; off > 0; off >>= 1) acc += __shfl_xor(acc, off, 64);
  if (lane == 0){
    if (kind == 0) ubuf[oi] = acc;
    else if (kind == 1) c0buf[oi] = acc;
    else if (kind == 2){
      float w = acc*0.03125f;
      for (int b = 0; b < 4; b++) cba[(br_s*4 + b)*1152 + 1024 + br_r] = w;
    } else bqbk[oi] = acc;
  }
}

// cba[z*1152+l] = (hid[b][l].u_s + bqbk_s)/32
__global__ __launch_bounds__(256) void cba_k(const float* __restrict__ hid, const float* __restrict__ u,
                                             const float* __restrict__ bqbk, float* __restrict__ cba){
  int row = blockIdx.x*4 + (threadIdx.x >> 6);  // z*1024+l
  int lane = threadIdx.x & 63;
  int z = row >> 10, l = row & 1023, b = z & 3, s = z >> 2;
  const f4* hp = (const f4*)(hid + ((size_t)b*1024 + l)*1024);
  const f4* up = (const f4*)(u + s*1024);
  float acc = 0.0f;
  #pragma unroll
  for (int p = 0; p < 4; p++){
    f4 a = hp[lane + 64*p], c = up[lane + 64*p];
    acc += a[0]*c[0] + a[1]*c[1] + a[2]*c[2] + a[3]*c[3];
  }
  #pragma unroll
  for (int off = 32; off > 0; off >>= 1) acc += __shfl_xor(acc, off, 64);
  if (!lane) cba[z*1152 + l] = (acc + bqbk[s])*0.03125f;
}

// meanH2[b*1024+d] = (1/1024) * sum_l H2T[b][d][l]
__global__ __launch_bounds__(256) void meanh2_k(const u16* __restrict__ H2T, float* __restrict__ mh){
  int row = blockIdx.x*4 + (threadIdx.x >> 6);
  int lane = threadIdx.x & 63;
  const u16* p = H2T + (size_t)row*1024 + lane*16;
  float s = 0.0f;
  #pragma unroll
  for (int j = 0; j < 16; j++) s += b2f(p[j]);
  #pragma unroll
  for (int off = 32; off > 0; off >>= 1) s += __shfl_xor(s, off, 64);
  if (lane == 0) mh[row] = s * 0.0009765625f;
}

// row softmax: bf16 scores + rel gather -> probs f32 (d_out) + bf16 attnP;
// a row's LAST active iter (iter == w-1) also writes its uniform tail slots w..7
__global__ __launch_bounds__(256) void softmax_k(const u16* __restrict__ scB, float* __restrict__ outF,
                                                 u16* __restrict__ attnP, const float* __restrict__ qrelb,
                                                 const int* __restrict__ cnt, const int* __restrict__ perm,
                                                 const int* __restrict__ spw, int iter){
  int z = blockIdx.x >> 10, c = blockIdx.x & 1023;
  int s = z >> 2, b = z & 3;
  if (c >= cnt[b*8 + iter]) return;
  int ro = perm[b*1024 + c];
  __shared__ float qr[33];
  __shared__ float red[8];
  if (threadIdx.x < 33) qr[threadIdx.x] = qrelb[((size_t)z*1024 + c)*33 + threadIdx.x];
  __syncthreads();
  const u16* sc = scB + ((size_t)z*1024 + c)*1024;
  float* po = outF + (size_t)s*33554432ull + (((size_t)(b*1024 + ro))*8 + (size_t)iter)*1024;
  u16* pr = attnP + ((size_t)z*1024 + c)*1024;
  int t = threadIdx.x;
  float v[4]; float mx = -1e30f;
  #pragma unroll
  for (int j = 0; j < 4; j++){
    int col = t + j*256;
    int d = col - ro; d = d < -16 ? -16 : (d > 16 ? 16 : d);
    v[j] = b2f(sc[col]) + qr[d + 16];
    mx = fmaxf(mx, v[j]);
  }
  #pragma unroll
  for (int off = 32; off > 0; off >>= 1) mx = fmaxf(mx, __shfl_xor(mx, off, 64));
  int wv = t >> 6, ln = t & 63;
  if (ln == 0) red[wv] = mx;
  __syncthreads();
  mx = fmaxf(fmaxf(red[0], red[1]), fmaxf(red[2], red[3]));
  float sm = 0.0f;
  #pragma unroll
  for (int j = 0; j < 4; j++){ v[j] = __expf(v[j] - mx); sm += v[j]; }
  #pragma unroll
  for (int off = 32; off > 0; off >>= 1) sm += __shfl_xor(sm, off, 64);
  if (ln == 0) red[4 + wv] = sm;
  __syncthreads();
  sm = red[4] + red[5] + red[6] + red[7];
  float inv = 1.0f / sm;
  #pragma unroll
  for (int j = 0; j < 4; j++){
    float pv = v[j] * inv;
    po[t + j*256] = pv;
    pr[t + j*256] = f2b(pv);
  }
  int w = spw[b*1024 + ro];
  if (iter == w - 1 && w < 8){
    f4 u = {0.0009765625f, 0.0009765625f, 0.0009765625f, 0.0009765625f};
    for (int j = 1; j <= 7 - iter; j++)
      ((f4*)(po + (size_t)j*1024))[t] = u;
  }
}

// ---------------- MFMA GEMM, 128x128 tile, BK=64, depth-2 counted-vmcnt + swizzle + setprio
// MODE 0: z<2: WT[s] = wqB[s]@wkB[s]^T ; z>=2 (y==0): Mx rel rows = (relB[s]@wqB[s]^T)/32
// MODE 2: hn[z]  = relu(attnP[z]@H2T + hp[z&am]@W1 + sp_b (+mh))  compacted
// MODE 4: sc     = hn[z&am] @ Mx[z]^T (+cba) -> scB / qrelb       compacted
// MODE 5: z<8 -> Mx[z] = (hidB[b]@WT[s]^T + c0)/32 ; z>=8 -> H2T[z-8] = W2^T @ hidB
template<int MODE>
__global__ __launch_bounds__(256) void gemm_k(
    const u16* __restrict__ A_, const u16* __restrict__ B_,
    const u16* __restrict__ A2_, const u16* __restrict__ B2_,
    const float* __restrict__ e0, const float* __restrict__ e1,
    u16* __restrict__ outB, u16* __restrict__ outB2, float* __restrict__ qrelb,
    const int* __restrict__ cnt, int iter, int azmask)
{
  const int z = blockIdx.z;
  const size_t LD = 1024*1024;
  const int bm = blockIdx.y*128, bn = blockIdx.x*128;
  int s = z >> 2, b = z & 3;
  bool m5h2 = false;                 // MODE5: H2T sub-job
  if constexpr (MODE == 5){ if (z >= 8){ m5h2 = true; b = z - 8; s = 0; } }

  int cntv = 1024;
  if constexpr (MODE == 2 || MODE == 4){
    cntv = cnt[b*8 + iter];
    if (bm >= cntv) return;
  }

  const u16 *A1, *B1, *A2, *B2;
  int lda1 = 1024, ldb1 = 1024, lda2 = 1024, ldb2 = 1024, K = 1024, K1 = 1024;

  if constexpr (MODE == 0){
    if (z < 2){ A1 = A_ + (size_t)z*LD; B1 = B_ + (size_t)z*LD; }
    else {
      if (blockIdx.y > 0) return;          // rel rows fit in one 128-row tile
      A1 = A2_ + (size_t)(z-2)*131072;     // relB (padded 128x1024 per s)
      B1 = A_ + (size_t)(z-2)*LD;          // wqB
    }
    A2=A1; B2=B1;
  }
  else if constexpr (MODE == 2){
    A1 = A_ + (size_t)z*LD; B1 = B_ + (size_t)b*LD;
    A2 = A2_ + (size_t)(z & azmask)*LD; B2 = B2_; ldb2 = 2048;
    if (iter == 0){ K = 1024; K1 = 0; } else { K = 2048; K1 = 1024; }
  }
  else if constexpr (MODE == 4){ A1 = A_ + (size_t)(z & azmask)*LD; B1 = B_ + (size_t)z*1179648; A2=A1; B2=B1; }
  else { // MODE 5
    if (!m5h2){ A1 = A_ + (size_t)b*LD; B1 = B_ + (size_t)s*LD; }
    else      { A1 = A2_ + 1024; lda1 = 2048; B1 = B2_ + (size_t)b*LD; }
    A2=A1; B2=B1; lda2=lda1;
  }

  // 2 bufs x [2 K-halves][128 rows][32 cols] bf16 = 2 x 16 KB per operand (64 KB total)
  __shared__ __align__(16) u16 lA[16384];
  __shared__ __align__(16) u16 lB[16384];
  const int tid = threadIdx.x, wv = tid >> 6, lane = tid & 63;
  const int wr = (wv >> 1)*64, wc = (wv & 1)*64;
  const int fr = lane & 15, kh = lane >> 4;
  const int stRow = (lane >> 2);
  // T2 swizzle both-sides (rule #21): 16B slot' = slot ^ ((row&3)^((row>>2)&3))
  const int ssw  = ((lane >> 2) & 3) ^ ((lane >> 4) & 3);
  const int stCe = ((lane & 3) ^ ssw)*8;
  const int fsw  = (fr & 3) ^ ((fr >> 2) & 3);
  const int rdSl = (kh ^ fsw)*8;

  auto stage = [&](int bufsel, int k0s){
    const u16 *As, *Bs; int kk, la, lb;
    if (k0s < K1){ As = A1; Bs = B1; kk = k0s; la = lda1; lb = ldb1; }
    else         { As = A2; Bs = B2; kk = k0s - K1; la = lda2; lb = ldb2; }
    #pragma unroll
    for (int c = 0; c < 4; c++){
      const int n = wv*4 + c;                 // chunk 0..15 (1KB each)
      const int h = n >> 3;
      const int rl = (n & 7)*16 + stRow;
      const int ke = kk + h*32 + stCe;
      gload16(As + (size_t)(bm + rl)*la + ke, (char*)lA + bufsel*16384 + n*1024);
      gload16(Bs + (size_t)(bn + rl)*lb + ke, (char*)lB + bufsel*16384 + n*1024);
    }
  };

  f4 acc[4][4];
  #pragma unroll
  for (int i = 0; i < 4; i++)
    #pragma unroll
    for (int j = 0; j < 4; j++)
      acc[i][j] = f4{0.f, 0.f, 0.f, 0.f};

  stage(0, 0);
  stage(1, 64);               // K >= 128 always here

  int cur = 0;
  for (int k0 = 0; k0 < K; k0 += 64){
    // stage(t) landed (8 own loads of stage(t+1) may remain in flight)
    if (k0 + 64 < K) asm volatile("s_waitcnt vmcnt(8)" ::: "memory");
    else             asm volatile("s_waitcnt vmcnt(0)" ::: "memory");
    __builtin_amdgcn_s_barrier();           // all waves' stage(t) visible
    asm volatile("" ::: "memory");
    const u16* bufA = lA + cur*8192;
    const u16* bufB = lB + cur*8192;
    bh8 af[2][4], bfr[2][4];
    #pragma unroll
    for (int h = 0; h < 2; h++){
      #pragma unroll
      for (int i = 0; i < 4; i++){
        af[h][i]  = *(const bh8*)&bufA[h*4096 + (wr + i*16 + fr)*32 + rdSl];
        bfr[h][i] = *(const bh8*)&bufB[h*4096 + (wc + i*16 + fr)*32 + rdSl];
      }
    }
    if (k0 + 128 < K){
      asm volatile("s_waitcnt lgkmcnt(0)" ::: "memory");   // my reads done
      __builtin_amdgcn_sched_barrier(0);
      __builtin_amdgcn_s_barrier();           // all waves done reading buf[cur]
      asm volatile("" ::: "memory");
      stage(cur, k0 + 128);                   // refill buf[cur] for step t+2
    }
    __builtin_amdgcn_s_setprio(1);
    #pragma unroll
    for (int h = 0; h < 2; h++)
      #pragma unroll
      for (int i = 0; i < 4; i++)
        #pragma unroll
        for (int j = 0; j < 4; j++)
          acc[i][j] = __builtin_amdgcn_mfma_f32_16x16x32_bf16(af[h][i], bfr[h][j], acc[i][j], 0, 0, 0);
    __builtin_amdgcn_s_setprio(0);
    cur ^= 1;
  }

  const int rw = (lane >> 4)*4, cl = lane & 15;
  #pragma unroll
  for (int i = 0; i < 4; i++){
    #pragma unroll
    for (int r = 0; r < 4; r++){
      const int row = bm + wr + i*16 + rw + r;
      if constexpr (MODE == 2 || MODE == 4){ if (row >= cntv) continue; }
      #pragma unroll
      for (int j = 0; j < 4; j++){
        const int col = bn + wc + j*16 + cl;
        float v = acc[i][j][r];
        if constexpr (MODE == 0){
          if (z < 2){
            outB[(size_t)z*LD + (size_t)row*1024 + col] = f2b(v);
          } else if (row < 33){
            u16 vv = f2b(v*0.03125f);
            size_t o = (size_t)(1024 + row)*1024 + col;
            int sx = z - 2;
            #pragma unroll
            for (int bb = 0; bb < 4; bb++)
              outB2[(size_t)(sx*4 + bb)*1179648 + o] = vv;
          }
        } else if constexpr (MODE == 2){
          v += e0[col];
          if (e1) v += e1[b*1024 + col];
          v = fmaxf(v, 0.0f);
          outB[(size_t)z*LD + (size_t)row*1024 + col] = f2b(v);
        } else if constexpr (MODE == 5){
          if (!m5h2)
            outB[(size_t)z*1179648 + (size_t)row*1024 + col] = f2b((v + e0[s*1024 + col])*0.03125f);
          else
            outB2[(size_t)b*LD + (size_t)row*1024 + col] = f2b(v);
        } else {
          v += e0[z*1152 + col];
          if (col < 1024){
            outB[((size_t)z*1024 + row)*1024 + col] = f2b(v);
          } else {
            int rr = col - 1024;
            if (rr < 33) qrelb[((size_t)z*1024 + row)*33 + rr] = v;
          }
        }
      }
    }
  }
}

// ---------------- host ----------------

extern "C" void kernel_launch(void* const* d_in, const int* in_sizes, int n_in,
                              void* d_out, int out_size, void* d_ws, size_t ws_size,
                              hipStream_t stream)
{
  const float* hid    = (const float*)d_in[0];
  const float* srch   = (const float*)d_in[1];
  const int*   spw    = (const int*)d_in[2];
  const float* wq_st  = (const float*)d_in[6];
  const float* bq_st  = (const float*)d_in[7];
  const float* wk_st  = (const float*)d_in[8];
  const float* bk_st  = (const float*)d_in[9];
  const float* rel_st = (const float*)d_in[10];
  const float* wq_ed  = (const float*)d_in[11];
  const float* bq_ed  = (const float*)d_in[12];
  const float* wk_ed  = (const float*)d_in[13];
  const float* bk_ed  = (const float*)d_in[14];
  const float* rel_ed = (const float*)d_in[15];
  const float* sp_w   = (const float*)d_in[16];
  const float* sp_b   = (const float*)d_in[17];
  float* out = (float*)d_out;

  const size_t LD = 1024*1024;
  char* p = (char*)d_ws;
  u16* hidB  = (u16*)p; p += 4*LD*2;
  u16* wqB   = (u16*)p; p += 2*LD*2;
  u16* wkB   = (u16*)p; p += 2*LD*2;
  u16* relB  = (u16*)p; p += 2*131072*2;          // 2 x [128][1024] bf16 (rows >=33 garbage ok)
  u16* spwT  = (u16*)p; p += 2*LD*2;
  u16* WT    = (u16*)p; p += 2*LD*2;
  u16* H2T   = (u16*)p; p += 4*LD*2;
  u16* Mx    = (u16*)p; p += 8ull*1179648*2;      // 8 x [1152][1024]
  u16* attnP = (u16*)p; p += 8*LD*2;
  u16* hbufA = (u16*)p; p += 8*LD*2;
  u16* hbufB = (u16*)p; p += 8*LD*2;
  u16* scB   = (u16*)p; p += 8*LD*2;
  float* qrelb  = (float*)p; p += 8*1024*33*4;
  float* cba    = (float*)p; p += 8*1152*4;
  float* ubuf   = (float*)p; p += 2048*4;
  float* c0buf  = (float*)p; p += 2048*4;
  float* bqbk   = (float*)p; p += 64;
  float* meanH2 = (float*)p; p += 4*1024*4;
  int*   perm   = (int*)p;   p += 4*1024*4;
  int*   cnt    = (int*)p;   p += 1024;

  const dim3 t256(256);

  // --- precompute ---
  convall_k<<<8258, t256, 0, stream>>>(hid, wq_st, wq_ed, wk_st, wk_ed, rel_st, rel_ed,
                                       hidB, wqB, wkB, relB);
  sort_k<<<4, t256, 0, stream>>>(spw, perm, cnt, out + 67108864ull);
  gather_k<<<4096, t256, 0, stream>>>(srch, perm, hbufA);
  uniform0_k<<<4096, t256, 0, stream>>>(spw, out);
  trans_k<<<dim3(32,64), t256, 0, stream>>>(sp_w, spwT, 2048, 1024);
  dots_k<<<1041, t256, 0, stream>>>(wq_st, wq_ed, wk_st, wk_ed, bq_st, bq_ed, bk_st, bk_ed,
                                    rel_st, rel_ed, ubuf, c0buf, bqbk, cba);
  cba_k<<<2048, t256, 0, stream>>>(hid, ubuf, bqbk, cba);

  // z<2: WT ; z>=2: Mx rel rows (rel@wq^T /32, 4 b-copies)
  gemm_k<0><<<dim3(8,8,4), t256, 0, stream>>>(wqB, wkB, relB, nullptr, nullptr, nullptr,
                                              WT, Mx, nullptr, nullptr, 0, 7);
  // merged: z<8 -> Mx (hidB@WT^T), z>=8 -> H2T (spwT lower half @ hidB)
  gemm_k<5><<<dim3(8,8,12), t256, 0, stream>>>(hidB, WT, spwT, hidB, c0buf, nullptr,
                                               Mx, H2T, nullptr, nullptr, 0, 7);
  meanh2_k<<<1024, t256, 0, stream>>>(H2T, meanH2);

  u16* hp = hbufA; u16* hn = hbufB;
  for (int i = 0; i < 8; i++){
    // i==0: hn identical for st/ed (no attnP term) -> compute z=0..3 only
    int g2z = (i == 0) ? 4 : 8;
    int am2 = (i <= 1) ? 3 : 7;   // hp buffer has 4 z-copies at i=0 (gather) and i=1 (hn from i=0)
    gemm_k<2><<<dim3(8,8,g2z), t256, 0, stream>>>(attnP, H2T, hp, spwT, sp_b,
                                                  (i == 0) ? meanH2 : nullptr,
                                                  hn, nullptr, nullptr, cnt, i, am2);
    int am4 = (i == 0) ? 3 : 7;
    gemm_k<4><<<dim3(9,8,8), t256, 0, stream>>>(hn, Mx, nullptr, nullptr, cba, nullptr,
                                                scB, nullptr, qrelb, cnt, i, am4);
    softmax_k<<<8192, t256, 0, stream>>>(scB, out, attnP, qrelb, cnt, perm, spw, i);
    u16* tmp = hp; hp = hn; hn = tmp;
  }
}